// Round 3
// baseline (4273.678 us; speedup 1.0000x reference)
//
#include <hip/hip_runtime.h>
#include <hip/hip_bf16.h>

// ---------------- problem constants ----------------
#define B_ 2
#define F_ 16
#define Hs 32
#define Ws 32
#define C0 320
#define CEXP 512
#define D_INNER 1024
#define NHEADS 16
#define HEADDIM 64
#define D_STATE 128
#define D_CONV 4
#define CONV_DIM (D_INNER + 2*D_STATE)              // 1280
#define D_IN_PROJ (2*D_INNER + 2*D_STATE + NHEADS)  // 2320
#define GROUPS 32
#define NB (B_*F_)        // 32 frames
#define HW (Hs*Ws)        // 1024 spatial
#define NSEQ (B_*HW)      // 2048 sequences
#define NTOK (NSEQ*F_)    // 32768 tokens
#define NCHUNK 8
#define SEQ_PER (NSEQ/NCHUNK)   // 256
#define TOK_PER (SEQ_PER*F_)    // 4096

// ---------------- GroupNorm ----------------
__global__ __launch_bounds__(256) void gn_kernel(const float* __restrict__ x,
    const float* __restrict__ w, const float* __restrict__ b, float* __restrict__ out)
{
  const int CG = C0/GROUPS;            // 10
  const int NEL = CG*HW;               // 10240
  int g = blockIdx.x, n = blockIdx.y;
  const float* xp = x + ((size_t)n*C0 + (size_t)g*CG)*HW;
  float* op = out + ((size_t)n*C0 + (size_t)g*CG)*HW;
  float s = 0.f, ss = 0.f;
  for (int i = threadIdx.x; i < NEL; i += 256){ float v = xp[i]; s += v; ss += v*v; }
  __shared__ float rs[256], rq[256];
  rs[threadIdx.x] = s; rq[threadIdx.x] = ss;
  __syncthreads();
  for (int o = 128; o > 0; o >>= 1){
    if (threadIdx.x < o){ rs[threadIdx.x] += rs[threadIdx.x+o]; rq[threadIdx.x] += rq[threadIdx.x+o]; }
    __syncthreads();
  }
  float mu  = rs[0] / NEL;
  float var = rq[0] / NEL - mu*mu;
  float inv = rsqrtf(var + 1e-5f);
  for (int i = threadIdx.x; i < NEL; i += 256){
    int c = g*CG + i/HW;
    op[i] = (xp[i] - mu)*inv*w[c] + b[c];
  }
}

// ---------------- GEMM NN: Y[z] = Wm(MxK) * X[z](KxN) (+bias[m]) (+resid+gamma) ----------------
__global__ __launch_bounds__(256) void gemm_nn_kernel(
    const float* __restrict__ Wm, const float* __restrict__ X,
    const float* __restrict__ bias, float* __restrict__ Yo,
    int M, int N, int K,
    const float* __restrict__ resid, const float* __restrict__ gammap)
{
  __shared__ float As[16][65];
  __shared__ float Bs[16][65];
  const int tid = threadIdx.x;
  const int tx = tid & 15, ty = tid >> 4;
  const int m0 = blockIdx.y*64, n0 = blockIdx.x*64;
  const size_t zb = (size_t)blockIdx.z * K * N;
  const size_t zo = (size_t)blockIdx.z * M * N;
  const int lrow = tid >> 2, lk = (tid & 3)*4;   // A-tile load: 64 rows x 16 k
  const int bk = tid >> 4,  bn = (tid & 15)*4;   // B-tile load: 16 k x 64 n
  float acc[4][4] = {{0.f}};
  for (int k0 = 0; k0 < K; k0 += 16){
    float4 av = *(const float4*)&Wm[(size_t)(m0+lrow)*K + k0 + lk];
    As[lk+0][lrow]=av.x; As[lk+1][lrow]=av.y; As[lk+2][lrow]=av.z; As[lk+3][lrow]=av.w;
    float4 bv = *(const float4*)&X[zb + (size_t)(k0+bk)*N + n0 + bn];
    Bs[bk][bn+0]=bv.x; Bs[bk][bn+1]=bv.y; Bs[bk][bn+2]=bv.z; Bs[bk][bn+3]=bv.w;
    __syncthreads();
    #pragma unroll
    for (int k = 0; k < 16; k++){
      float a0=As[k][ty*4+0], a1=As[k][ty*4+1], a2=As[k][ty*4+2], a3=As[k][ty*4+3];
      float b0=Bs[k][tx*4+0], b1=Bs[k][tx*4+1], b2=Bs[k][tx*4+2], b3=Bs[k][tx*4+3];
      acc[0][0]+=a0*b0; acc[0][1]+=a0*b1; acc[0][2]+=a0*b2; acc[0][3]+=a0*b3;
      acc[1][0]+=a1*b0; acc[1][1]+=a1*b1; acc[1][2]+=a1*b2; acc[1][3]+=a1*b3;
      acc[2][0]+=a2*b0; acc[2][1]+=a2*b1; acc[2][2]+=a2*b2; acc[2][3]+=a2*b3;
      acc[3][0]+=a3*b0; acc[3][1]+=a3*b1; acc[3][2]+=a3*b2; acc[3][3]+=a3*b3;
    }
    __syncthreads();
  }
  float gm = gammap ? *gammap : 0.f;
  #pragma unroll
  for (int i = 0; i < 4; i++){
    int m = m0 + ty*4 + i;
    float bb = bias ? bias[m] : 0.f;
    #pragma unroll
    for (int j = 0; j < 4; j++){
      int n = n0 + tx*4 + j;
      float v = acc[i][j] + bb;
      if (resid) v = resid[zo + (size_t)m*N + n] + gm*v;
      Yo[zo + (size_t)m*N + n] = v;
    }
  }
}

// ---------------- expand GEMM with fused frames->sequence transpose epilogue ----------------
// computes E[z][m][n] = sum_k Wm[m][k]*X[z][k][n] + bias[m], writes to
// U[((b*HW + n)*F_ + f)*CEXP + m] where z = b*F_+f.  M=CEXP, N=HW, K=C0.
__global__ __launch_bounds__(256) void gemm_nn_seq_kernel(
    const float* __restrict__ Wm, const float* __restrict__ X,
    const float* __restrict__ bias, float* __restrict__ U,
    int M, int N, int K)
{
  __shared__ float As[16][65];
  __shared__ float Bs[16][65];
  const int tid = threadIdx.x;
  const int tx = tid & 15, ty = tid >> 4;
  const int m0 = blockIdx.y*64, n0 = blockIdx.x*64;
  const size_t zb = (size_t)blockIdx.z * K * N;
  const int lrow = tid >> 2, lk = (tid & 3)*4;
  const int bk = tid >> 4,  bn = (tid & 15)*4;
  float acc[4][4] = {{0.f}};
  for (int k0 = 0; k0 < K; k0 += 16){
    float4 av = *(const float4*)&Wm[(size_t)(m0+lrow)*K + k0 + lk];
    As[lk+0][lrow]=av.x; As[lk+1][lrow]=av.y; As[lk+2][lrow]=av.z; As[lk+3][lrow]=av.w;
    float4 bv = *(const float4*)&X[zb + (size_t)(k0+bk)*N + n0 + bn];
    Bs[bk][bn+0]=bv.x; Bs[bk][bn+1]=bv.y; Bs[bk][bn+2]=bv.z; Bs[bk][bn+3]=bv.w;
    __syncthreads();
    #pragma unroll
    for (int k = 0; k < 16; k++){
      float a0=As[k][ty*4+0], a1=As[k][ty*4+1], a2=As[k][ty*4+2], a3=As[k][ty*4+3];
      float b0=Bs[k][tx*4+0], b1=Bs[k][tx*4+1], b2=Bs[k][tx*4+2], b3=Bs[k][tx*4+3];
      acc[0][0]+=a0*b0; acc[0][1]+=a0*b1; acc[0][2]+=a0*b2; acc[0][3]+=a0*b3;
      acc[1][0]+=a1*b0; acc[1][1]+=a1*b1; acc[1][2]+=a1*b2; acc[1][3]+=a1*b3;
      acc[2][0]+=a2*b0; acc[2][1]+=a2*b1; acc[2][2]+=a2*b2; acc[2][3]+=a2*b3;
      acc[3][0]+=a3*b0; acc[3][1]+=a3*b1; acc[3][2]+=a3*b2; acc[3][3]+=a3*b3;
    }
    __syncthreads();
  }
  const int bb = blockIdx.z >> 4, f = blockIdx.z & (F_-1);
  #pragma unroll
  for (int i = 0; i < 4; i++){
    int m = m0 + ty*4 + i;
    float bv2 = bias[m];
    #pragma unroll
    for (int j = 0; j < 4; j++){
      int n = n0 + tx*4 + j;   // hw
      U[(((size_t)(bb*HW + n))*F_ + f)*CEXP + m] = acc[i][j] + bv2;
    }
  }
}

// ---------------- GEMM NT: C = A(MxK) * Bw(NxK)^T ----------------
__global__ __launch_bounds__(256) void gemm_nt_kernel(
    const float* __restrict__ A, const float* __restrict__ Bw,
    float* __restrict__ C, int M, int N, int K)
{
  __shared__ float As[16][65];
  __shared__ float Bs[16][65];
  const int tid = threadIdx.x;
  const int tx = tid & 15, ty = tid >> 4;
  const int m0 = blockIdx.y*64, n0 = blockIdx.x*64;
  const int lrow = tid >> 2;        // 0..63
  const int lk   = (tid & 3)*4;     // 0,4,8,12
  const bool bok = (n0 + lrow) < N;
  const float* Arow = A  + (size_t)(m0 + lrow)*K + lk;
  const float* Brow = Bw + (size_t)(n0 + (bok ? lrow : 0))*K + lk;
  float acc[4][4] = {{0.f}};
  for (int k0 = 0; k0 < K; k0 += 16){
    float4 av = *(const float4*)(Arow + k0);
    float4 bv = bok ? *(const float4*)(Brow + k0) : make_float4(0.f,0.f,0.f,0.f);
    As[lk+0][lrow]=av.x; As[lk+1][lrow]=av.y; As[lk+2][lrow]=av.z; As[lk+3][lrow]=av.w;
    Bs[lk+0][lrow]=bv.x; Bs[lk+1][lrow]=bv.y; Bs[lk+2][lrow]=bv.z; Bs[lk+3][lrow]=bv.w;
    __syncthreads();
    #pragma unroll
    for (int k = 0; k < 16; k++){
      float a0=As[k][ty*4+0], a1=As[k][ty*4+1], a2=As[k][ty*4+2], a3=As[k][ty*4+3];
      float b0=Bs[k][tx*4+0], b1=Bs[k][tx*4+1], b2=Bs[k][tx*4+2], b3=Bs[k][tx*4+3];
      acc[0][0]+=a0*b0; acc[0][1]+=a0*b1; acc[0][2]+=a0*b2; acc[0][3]+=a0*b3;
      acc[1][0]+=a1*b0; acc[1][1]+=a1*b1; acc[1][2]+=a1*b2; acc[1][3]+=a1*b3;
      acc[2][0]+=a2*b0; acc[2][1]+=a2*b1; acc[2][2]+=a2*b2; acc[2][3]+=a2*b3;
      acc[3][0]+=a3*b0; acc[3][1]+=a3*b1; acc[3][2]+=a3*b2; acc[3][3]+=a3*b3;
    }
    __syncthreads();
  }
  #pragma unroll
  for (int i = 0; i < 4; i++){
    int m = m0 + ty*4 + i;
    #pragma unroll
    for (int j = 0; j < 4; j++){
      int n = n0 + tx*4 + j;
      if (n < N) C[(size_t)m*N + n] = acc[i][j];
    }
  }
}

// ---------------- out_proj GEMM NT with fused sequence->frames transpose epilogue ----------------
// A: Y chunk (TOK_PER x D_INNER), Bw: out_proj_w (CEXP x D_INNER).
// token m -> (seq_local, f); global seq = c0seq + seq_local -> (b, hw).
// write R[((b*F_+f)*CEXP + n)*HW + hw]
__global__ __launch_bounds__(256) void gemm_nt_frames_kernel(
    const float* __restrict__ A, const float* __restrict__ Bw,
    float* __restrict__ R, int K, int c0seq)
{
  __shared__ float As[16][65];
  __shared__ float Bs[16][65];
  const int tid = threadIdx.x;
  const int tx = tid & 15, ty = tid >> 4;
  const int m0 = blockIdx.y*64, n0 = blockIdx.x*64;
  const int lrow = tid >> 2;
  const int lk   = (tid & 3)*4;
  const float* Arow = A  + (size_t)(m0 + lrow)*K + lk;
  const float* Brow = Bw + (size_t)(n0 + lrow)*K + lk;
  float acc[4][4] = {{0.f}};
  for (int k0 = 0; k0 < K; k0 += 16){
    float4 av = *(const float4*)(Arow + k0);
    float4 bv = *(const float4*)(Brow + k0);
    As[lk+0][lrow]=av.x; As[lk+1][lrow]=av.y; As[lk+2][lrow]=av.z; As[lk+3][lrow]=av.w;
    Bs[lk+0][lrow]=bv.x; Bs[lk+1][lrow]=bv.y; Bs[lk+2][lrow]=bv.z; Bs[lk+3][lrow]=bv.w;
    __syncthreads();
    #pragma unroll
    for (int k = 0; k < 16; k++){
      float a0=As[k][ty*4+0], a1=As[k][ty*4+1], a2=As[k][ty*4+2], a3=As[k][ty*4+3];
      float b0=Bs[k][tx*4+0], b1=Bs[k][tx*4+1], b2=Bs[k][tx*4+2], b3=Bs[k][tx*4+3];
      acc[0][0]+=a0*b0; acc[0][1]+=a0*b1; acc[0][2]+=a0*b2; acc[0][3]+=a0*b3;
      acc[1][0]+=a1*b0; acc[1][1]+=a1*b1; acc[1][2]+=a1*b2; acc[1][3]+=a1*b3;
      acc[2][0]+=a2*b0; acc[2][1]+=a2*b1; acc[2][2]+=a2*b2; acc[2][3]+=a2*b3;
      acc[3][0]+=a3*b0; acc[3][1]+=a3*b1; acc[3][2]+=a3*b2; acc[3][3]+=a3*b3;
    }
    __syncthreads();
  }
  #pragma unroll
  for (int i = 0; i < 4; i++){
    int m = m0 + ty*4 + i;                 // token_local
    int s = c0seq + (m >> 4);
    int f = m & (F_-1);
    int bb = s >> 10, hw = s & (HW-1);
    #pragma unroll
    for (int j = 0; j < 4; j++){
      int n = n0 + tx*4 + j;               // o
      R[(((size_t)(bb*F_ + f))*CEXP + n)*HW + hw] = acc[i][j];
    }
  }
}

// ---------------- fused conv1d + SSD + gate + RMSNorm, one block per sequence ----------------
__global__ __launch_bounds__(256,1) void ssm_kernel(
    const float* __restrict__ Zc,      // (SEQ_PER, F_, D_IN_PROJ)
    const float* __restrict__ conv_w,  // (CONV_DIM, 4)
    const float* __restrict__ conv_b,  // (CONV_DIM)
    const float* __restrict__ dt_bias, // (NHEADS)
    const float* __restrict__ A_log,   // (NHEADS)
    const float* __restrict__ Dp,      // (NHEADS)
    const float* __restrict__ rms_w,   // (D_INNER)
    float* __restrict__ Yc)            // (SEQ_PER, F_, D_INNER)
{
  __shared__ float xbc[F_][CONV_DIM];          // 80 KiB
  __shared__ float wts[F_][F_][NHEADS];        // 16 KiB
  __shared__ float dts[F_][NHEADS];
  __shared__ float cums[F_][NHEADS];
  __shared__ float scor[F_][F_];
  __shared__ float red[256];
  __shared__ float rinv[F_];
  const int tid = threadIdx.x;
  const float* Zb = Zc + (size_t)blockIdx.x * F_ * D_IN_PROJ;
  float*       Yb = Yc + (size_t)blockIdx.x * F_ * D_INNER;

  // dt = softplus(raw + dt_bias) : 16x16 by 256 threads
  {
    int t = tid >> 4, h = tid & 15;
    float v = Zb[t*D_IN_PROJ + (D_INNER + CONV_DIM) + h] + dt_bias[h];
    dts[t][h] = (v > 20.f) ? v : log1pf(expf(v));
  }
  __syncthreads();
  if (tid < NHEADS){
    float A = -expf(A_log[tid]);
    float c = 0.f;
    for (int t = 0; t < F_; t++){ c += dts[t][tid]*A; cums[t][tid] = c; }
  }
  // causal depthwise conv1d + silu
  for (int i = tid; i < F_*CONV_DIM; i += 256){
    int t = i / CONV_DIM, c = i - t*CONV_DIM;
    float acc = conv_b[c];
    #pragma unroll
    for (int k = 0; k < D_CONV; k++){
      int s = t + k - (D_CONV-1);
      if (s >= 0) acc += Zb[s*D_IN_PROJ + D_INNER + c] * conv_w[c*D_CONV + k];
    }
    xbc[t][c] = acc / (1.f + expf(-acc));
  }
  __syncthreads();
  // scores[t][s] = C[t] . B[s]
  {
    int t = tid >> 4, s = tid & 15;
    float acc = 0.f;
    for (int n = 0; n < D_STATE; n++)
      acc += xbc[t][D_INNER + D_STATE + n] * xbc[s][D_INNER + n];
    scor[t][s] = acc;
  }
  __syncthreads();
  // wts[t][s][h] = scores * exp(cum_t - cum_s) * dt_s  (s<=t)
  for (int i = tid; i < F_*F_*NHEADS; i += 256){
    int h = i & 15, s = (i >> 4) & 15, t = i >> 8;
    float v = 0.f;
    if (s <= t) v = scor[t][s] * expf(cums[t][h] - cums[s][h]) * dts[s][h];
    wts[t][s][h] = v;
  }
  __syncthreads();
  // y[t] = D_h*x[t] + sum_{s<=t} wts*x[s] ; then gate by silu(z); write back into xbc
  for (int rep = 0; rep < D_INNER/256; rep++){
    int col = rep*256 + tid;        // 0..1023, exclusive per thread
    int h = col >> 6;               // wave-uniform
    float Dh = Dp[h];
    float y[F_];
    #pragma unroll
    for (int t = 0; t < F_; t++){
      float acc = Dh * xbc[t][col];
      #pragma unroll
      for (int s = 0; s <= t; s++)
        acc += wts[t][s][h] * xbc[s][col];
      y[t] = acc;
    }
    #pragma unroll
    for (int t = 0; t < F_; t++){
      float z = Zb[t*D_IN_PROJ + col];
      float sg = 1.f / (1.f + expf(-z));
      xbc[t][col] = y[t] * z * sg;
    }
  }
  __syncthreads();
  // RMS over D_INNER per t
  {
    int t = tid >> 4, seg = tid & 15;
    float s = 0.f;
    for (int c = seg*64; c < seg*64 + 64; c++){ float v = xbc[t][c]; s += v*v; }
    red[tid] = s;
  }
  __syncthreads();
  if (tid < F_){
    float s = 0.f;
    for (int j = 0; j < 16; j++) s += red[tid*16 + j];
    rinv[tid] = rsqrtf(s / D_INNER + 1e-5f);
  }
  __syncthreads();
  for (int i = tid; i < F_*D_INNER; i += 256){
    int t = i >> 10, c = i & (D_INNER-1);
    Yb[i] = xbc[t][c] * rinv[t] * rms_w[c];
  }
}

// ---------------- launcher ----------------
// workspace layout (floats), total 52,428,800 floats = 200 MiB:
//   OFF_A = 0          (40 MiB)  GN out            } region [0, 20.97M) later
//   OFF_B = 10485760   (40 MiB)  proj_in out       } reused as frames R (64 MiB)
//   OFF_U = 20971520   (64 MiB)  U sequences
//   OFF_Z = 37748736   (40 MiB)  zxbcdt chunk (36.25) / collapse out (40)
//   OFF_Y = 48234496   (16 MiB)  ssm-out chunk
extern "C" void kernel_launch(void* const* d_in, const int* in_sizes, int n_in,
                              void* d_out, int out_size, void* d_ws, size_t ws_size,
                              hipStream_t stream)
{
  const float* x         = (const float*)d_in[0];
  const float* norm_w    = (const float*)d_in[1];
  const float* norm_b    = (const float*)d_in[2];
  const float* proj_in_w = (const float*)d_in[3];
  const float* proj_in_b = (const float*)d_in[4];
  const float* expand_w  = (const float*)d_in[5];
  const float* expand_b  = (const float*)d_in[6];
  const float* in_proj_w = (const float*)d_in[7];
  const float* conv_w    = (const float*)d_in[8];
  const float* conv_b    = (const float*)d_in[9];
  const float* dt_bias   = (const float*)d_in[10];
  const float* A_log     = (const float*)d_in[11];
  const float* Dvec      = (const float*)d_in[12];
  const float* rms_w     = (const float*)d_in[13];
  const float* out_proj_w= (const float*)d_in[14];
  const float* collapse_w= (const float*)d_in[15];
  const float* collapse_b= (const float*)d_in[16];
  const float* proj_out_w= (const float*)d_in[17];
  const float* proj_out_b= (const float*)d_in[18];
  const float* gamma     = (const float*)d_in[19];
  float* out = (float*)d_out;

  float* WS = (float*)d_ws;
  float* A  = WS;                       // GN out (frames, C0)
  float* Bp = WS + 10485760;            // proj_in out (frames, C0)
  float* R  = WS;                       // out_proj frames output (CEXP) — reuses A+B region
  float* U  = WS + 20971520;            // sequences (NSEQ, F_, CEXP)
  float* Z  = WS + 37748736;            // zxbcdt chunk / collapse out
  float* Yc = WS + 48234496;            // ssm out chunk

  // 1) GroupNorm: x -> A
  gn_kernel<<<dim3(GROUPS, NB), 256, 0, stream>>>(x, norm_w, norm_b, A);
  // 2) proj_in (320->320): A -> Bp
  gemm_nn_kernel<<<dim3(HW/64, C0/64, NB), 256, 0, stream>>>(
      proj_in_w, A, proj_in_b, Bp, C0, HW, C0, nullptr, nullptr);
  // 3) expand (320->512) fused with frames->seq transpose: Bp -> U
  gemm_nn_seq_kernel<<<dim3(HW/64, CEXP/64, NB), 256, 0, stream>>>(
      expand_w, Bp, expand_b, U, CEXP, HW, C0);
  // 4) chunked: in_proj GEMM -> ssm -> out_proj (fused seq->frames) into R
  for (int c = 0; c < NCHUNK; c++){
    const float* Uc = U + (size_t)c*TOK_PER*CEXP;
    gemm_nt_kernel<<<dim3((D_IN_PROJ+63)/64, TOK_PER/64), 256, 0, stream>>>(
        Uc, in_proj_w, Z, TOK_PER, D_IN_PROJ, CEXP);
    ssm_kernel<<<SEQ_PER, 256, 0, stream>>>(
        Z, conv_w, conv_b, dt_bias, A_log, Dvec, rms_w, Yc);
    gemm_nt_frames_kernel<<<dim3(CEXP/64, TOK_PER/64), 256, 0, stream>>>(
        Yc, out_proj_w, R, D_INNER, c*SEQ_PER);
  }
  // 5) collapse (512->320): R -> Z
  gemm_nn_kernel<<<dim3(HW/64, C0/64, NB), 256, 0, stream>>>(
      collapse_w, R, collapse_b, Z, C0, HW, CEXP, nullptr, nullptr);
  // 6) proj_out (320->320) + residual: Z -> out
  gemm_nn_kernel<<<dim3(HW/64, C0/64, NB), 256, 0, stream>>>(
      proj_out_w, Z, proj_out_b, out, C0, HW, C0, x, gamma);
}

// Round 4
// 2310.876 us; speedup vs baseline: 1.8494x; 1.8494x over previous
//
#include <hip/hip_runtime.h>
#include <hip/hip_bf16.h>

// ---------------- problem constants ----------------
#define B_ 2
#define F_ 16
#define Hs 32
#define Ws 32
#define C0 320
#define CEXP 512
#define D_INNER 1024
#define NHEADS 16
#define HEADDIM 64
#define D_STATE 128
#define D_CONV 4
#define CONV_DIM (D_INNER + 2*D_STATE)              // 1280
#define D_IN_PROJ (2*D_INNER + 2*D_STATE + NHEADS)  // 2320
#define NPAD 2432                                   // 19*128, padded in_proj rows
#define GROUPS 32
#define NB (B_*F_)        // 32 frames
#define HW (Hs*Ws)        // 1024 spatial
#define NSEQ (B_*HW)      // 2048 sequences
#define NTOK (NSEQ*F_)    // 32768 tokens
#define NCHUNK 8
#define SEQ_PER (NSEQ/NCHUNK)   // 256
#define TOK_PER (SEQ_PER*F_)    // 4096

typedef __bf16 bf16x8 __attribute__((ext_vector_type(8)));
typedef float f32x4 __attribute__((ext_vector_type(4)));

// ---------------- GroupNorm ----------------
__global__ __launch_bounds__(256) void gn_kernel(const float* __restrict__ x,
    const float* __restrict__ w, const float* __restrict__ b, float* __restrict__ out)
{
  const int CG = C0/GROUPS;            // 10
  const int NEL = CG*HW;               // 10240
  int g = blockIdx.x, n = blockIdx.y;
  const float* xp = x + ((size_t)n*C0 + (size_t)g*CG)*HW;
  float* op = out + ((size_t)n*C0 + (size_t)g*CG)*HW;
  float s = 0.f, ss = 0.f;
  for (int i = threadIdx.x; i < NEL; i += 256){ float v = xp[i]; s += v; ss += v*v; }
  __shared__ float rs[256], rq[256];
  rs[threadIdx.x] = s; rq[threadIdx.x] = ss;
  __syncthreads();
  for (int o = 128; o > 0; o >>= 1){
    if (threadIdx.x < o){ rs[threadIdx.x] += rs[threadIdx.x+o]; rq[threadIdx.x] += rq[threadIdx.x+o]; }
    __syncthreads();
  }
  float mu  = rs[0] / NEL;
  float var = rq[0] / NEL - mu*mu;
  float inv = rsqrtf(var + 1e-5f);
  for (int i = threadIdx.x; i < NEL; i += 256){
    int c = g*CG + i/HW;
    op[i] = (xp[i] - mu)*inv*w[c] + b[c];
  }
}

// ---------------- weight f32 -> bf16 conversion (with optional row padding) ----------------
__global__ __launch_bounds__(256) void cvt_pad_kernel(const float* __restrict__ w,
    __hip_bfloat16* __restrict__ o, int Nreal, int Npad, int K)
{
  int i = blockIdx.x*256 + threadIdx.x;
  if (i >= Npad*K) return;
  int n = i / K;
  int k = i - n*K;
  float v = (n < Nreal) ? w[(size_t)n*K + k] : 0.f;
  o[i] = __float2bfloat16(v);
}

// ---------------- GEMM NN f32: Y[z] = Wm(MxK) * X[z](KxN) (+bias[m]) (+resid+gamma) ----------------
__global__ __launch_bounds__(256) void gemm_nn_kernel(
    const float* __restrict__ Wm, const float* __restrict__ X,
    const float* __restrict__ bias, float* __restrict__ Yo,
    int M, int N, int K,
    const float* __restrict__ resid, const float* __restrict__ gammap)
{
  __shared__ float As[16][65];
  __shared__ float Bs[16][65];
  const int tid = threadIdx.x;
  const int tx = tid & 15, ty = tid >> 4;
  const int m0 = blockIdx.y*64, n0 = blockIdx.x*64;
  const size_t zb = (size_t)blockIdx.z * K * N;
  const size_t zo = (size_t)blockIdx.z * M * N;
  const int lrow = tid >> 2, lk = (tid & 3)*4;
  const int bk = tid >> 4,  bn = (tid & 15)*4;
  float acc[4][4] = {{0.f}};
  for (int k0 = 0; k0 < K; k0 += 16){
    float4 av = *(const float4*)&Wm[(size_t)(m0+lrow)*K + k0 + lk];
    As[lk+0][lrow]=av.x; As[lk+1][lrow]=av.y; As[lk+2][lrow]=av.z; As[lk+3][lrow]=av.w;
    float4 bv = *(const float4*)&X[zb + (size_t)(k0+bk)*N + n0 + bn];
    Bs[bk][bn+0]=bv.x; Bs[bk][bn+1]=bv.y; Bs[bk][bn+2]=bv.z; Bs[bk][bn+3]=bv.w;
    __syncthreads();
    #pragma unroll
    for (int k = 0; k < 16; k++){
      float a0=As[k][ty*4+0], a1=As[k][ty*4+1], a2=As[k][ty*4+2], a3=As[k][ty*4+3];
      float b0=Bs[k][tx*4+0], b1=Bs[k][tx*4+1], b2=Bs[k][tx*4+2], b3=Bs[k][tx*4+3];
      acc[0][0]+=a0*b0; acc[0][1]+=a0*b1; acc[0][2]+=a0*b2; acc[0][3]+=a0*b3;
      acc[1][0]+=a1*b0; acc[1][1]+=a1*b1; acc[1][2]+=a1*b2; acc[1][3]+=a1*b3;
      acc[2][0]+=a2*b0; acc[2][1]+=a2*b1; acc[2][2]+=a2*b2; acc[2][3]+=a2*b3;
      acc[3][0]+=a3*b0; acc[3][1]+=a3*b1; acc[3][2]+=a3*b2; acc[3][3]+=a3*b3;
    }
    __syncthreads();
  }
  float gm = gammap ? *gammap : 0.f;
  #pragma unroll
  for (int i = 0; i < 4; i++){
    int m = m0 + ty*4 + i;
    float bb = bias ? bias[m] : 0.f;
    #pragma unroll
    for (int j = 0; j < 4; j++){
      int n = n0 + tx*4 + j;
      float v = acc[i][j] + bb;
      if (resid) v = resid[zo + (size_t)m*N + n] + gm*v;
      Yo[zo + (size_t)m*N + n] = v;
    }
  }
}

// ---------------- expand GEMM, fused frames->sequence transpose, bf16 output ----------------
// U[((b*HW + n)*F_ + f)*CEXP + m] = (bf16)(sum_k Wm[m][k]*X[z][k][n] + bias[m]),  z=b*F_+f
__global__ __launch_bounds__(256) void gemm_nn_seq_kernel(
    const float* __restrict__ Wm, const float* __restrict__ X,
    const float* __restrict__ bias, __hip_bfloat16* __restrict__ U,
    int M, int N, int K)
{
  __shared__ float As[16][65];
  __shared__ float Bs[16][65];
  const int tid = threadIdx.x;
  const int tx = tid & 15, ty = tid >> 4;
  const int m0 = blockIdx.y*64, n0 = blockIdx.x*64;
  const size_t zb = (size_t)blockIdx.z * K * N;
  const int lrow = tid >> 2, lk = (tid & 3)*4;
  const int bk = tid >> 4,  bn = (tid & 15)*4;
  float acc[4][4] = {{0.f}};
  for (int k0 = 0; k0 < K; k0 += 16){
    float4 av = *(const float4*)&Wm[(size_t)(m0+lrow)*K + k0 + lk];
    As[lk+0][lrow]=av.x; As[lk+1][lrow]=av.y; As[lk+2][lrow]=av.z; As[lk+3][lrow]=av.w;
    float4 bv = *(const float4*)&X[zb + (size_t)(k0+bk)*N + n0 + bn];
    Bs[bk][bn+0]=bv.x; Bs[bk][bn+1]=bv.y; Bs[bk][bn+2]=bv.z; Bs[bk][bn+3]=bv.w;
    __syncthreads();
    #pragma unroll
    for (int k = 0; k < 16; k++){
      float a0=As[k][ty*4+0], a1=As[k][ty*4+1], a2=As[k][ty*4+2], a3=As[k][ty*4+3];
      float b0=Bs[k][tx*4+0], b1=Bs[k][tx*4+1], b2=Bs[k][tx*4+2], b3=Bs[k][tx*4+3];
      acc[0][0]+=a0*b0; acc[0][1]+=a0*b1; acc[0][2]+=a0*b2; acc[0][3]+=a0*b3;
      acc[1][0]+=a1*b0; acc[1][1]+=a1*b1; acc[1][2]+=a1*b2; acc[1][3]+=a1*b3;
      acc[2][0]+=a2*b0; acc[2][1]+=a2*b1; acc[2][2]+=a2*b2; acc[2][3]+=a2*b3;
      acc[3][0]+=a3*b0; acc[3][1]+=a3*b1; acc[3][2]+=a3*b2; acc[3][3]+=a3*b3;
    }
    __syncthreads();
  }
  const int bb = blockIdx.z >> 4, f = blockIdx.z & (F_-1);
  #pragma unroll
  for (int i = 0; i < 4; i++){
    int m = m0 + ty*4 + i;
    float bv2 = bias[m];
    #pragma unroll
    for (int j = 0; j < 4; j++){
      int n = n0 + tx*4 + j;   // hw
      U[(((size_t)(bb*HW + n))*F_ + f)*CEXP + m] = __float2bfloat16(acc[i][j] + bv2);
    }
  }
}

// ---------------- bf16 MFMA GEMM NT: C = A(MxK) * Bw(NpadxK)^T ----------------
// 128x128 tile, BK=32, 4 waves (2x2), each wave 64x64 via 4x4 16x16x32 mfma frags.
// LDS tiles [128 rows][32 k] bf16, 16B-granule XOR swizzle: slot ^= (row>>1)&3
// -> 2-way max bank aliasing on both ds_write_b128 and ds_read_b128 (free).
// MODE 0: C[m*Nreal+n] (guard n<Nreal).
// MODE 1: seq->frames epilogue: R[((bb*F_+f)*CEXP + n)*HW + hw].
template<int MODE>
__global__ __launch_bounds__(256) void mfma_nt_kernel(
    const __hip_bfloat16* __restrict__ A,   // M x K
    const __hip_bfloat16* __restrict__ Bw,  // Npad x K
    float* __restrict__ C,
    int M, int Nreal, int K, int c0seq)
{
  __shared__ unsigned short As[128*32];
  __shared__ unsigned short Bs[128*32];
  const int tid = threadIdx.x;
  const int lane = tid & 63;
  const int m0 = blockIdx.y * 128;
  const int n0 = blockIdx.x * 128;

  // staging geometry: thread t covers global/LDS rows {t>>2, 64+(t>>2)}, slot t&3
  const int row0 = tid >> 2;              // 0..63
  const int sl   = tid & 3;               // 16B slot within 64B row
  const int row1 = row0 + 64;
  const int sw0  = sl ^ ((row0 >> 1) & 3);
  const int sw1  = sl ^ ((row1 >> 1) & 3);
  const size_t Aoff0 = (size_t)(m0 + row0)*K + sl*8;
  const size_t Aoff1 = (size_t)(m0 + row1)*K + sl*8;
  const size_t Boff0 = (size_t)(n0 + row0)*K + sl*8;
  const size_t Boff1 = (size_t)(n0 + row1)*K + sl*8;
  const int wp0 = row0*32 + sw0*8;        // ushort units
  const int wp1 = row1*32 + sw1*8;

  // fragment read offsets (ushort units), swizzled per-row
  const int wid = tid >> 6, wr = wid >> 1, wc = wid & 1;
  const int fr = lane & 15, ks = lane >> 4;
  int aoff[4], boff[4];
  #pragma unroll
  for (int i = 0; i < 4; i++){
    int ra = wr*64 + i*16 + fr;
    aoff[i] = ra*32 + ((ks ^ ((ra>>1)&3))<<3);
    int rb = wc*64 + i*16 + fr;
    boff[i] = rb*32 + ((ks ^ ((rb>>1)&3))<<3);
  }

  f32x4 acc[4][4];
  #pragma unroll
  for (int mi = 0; mi < 4; mi++)
    #pragma unroll
    for (int ni = 0; ni < 4; ni++)
      acc[mi][ni] = (f32x4)(0.f);

  for (int k0 = 0; k0 < K; k0 += 32){
    uint4 a0 = *(const uint4*)(A  + Aoff0 + k0);
    uint4 a1 = *(const uint4*)(A  + Aoff1 + k0);
    uint4 b0 = *(const uint4*)(Bw + Boff0 + k0);
    uint4 b1 = *(const uint4*)(Bw + Boff1 + k0);
    __syncthreads();                       // all waves done reading prev tile
    *(uint4*)&As[wp0] = a0;
    *(uint4*)&As[wp1] = a1;
    *(uint4*)&Bs[wp0] = b0;
    *(uint4*)&Bs[wp1] = b1;
    __syncthreads();                       // tile visible
    bf16x8 af[4], bfv[4];
    #pragma unroll
    for (int i = 0; i < 4; i++){
      af[i]  = *(const bf16x8*)&As[aoff[i]];
      bfv[i] = *(const bf16x8*)&Bs[boff[i]];
    }
    #pragma unroll
    for (int mi = 0; mi < 4; mi++)
      #pragma unroll
      for (int ni = 0; ni < 4; ni++)
        acc[mi][ni] = __builtin_amdgcn_mfma_f32_16x16x32_bf16(af[mi], bfv[ni], acc[mi][ni], 0, 0, 0);
  }

  #pragma unroll
  for (int mi = 0; mi < 4; mi++){
    #pragma unroll
    for (int ni = 0; ni < 4; ni++){
      #pragma unroll
      for (int i = 0; i < 4; i++){
        int m = m0 + wr*64 + mi*16 + (lane>>4)*4 + i;   // C/D: row=(lane>>4)*4+reg
        int n = n0 + wc*64 + ni*16 + (lane&15);          //      col=lane&15
        float v = acc[mi][ni][i];
        if (MODE == 0){
          if (n < Nreal) C[(size_t)m*Nreal + n] = v;
        } else {
          int sq = c0seq + (m >> 4);
          int f  = m & (F_-1);
          int bb = sq >> 10, hw = sq & (HW-1);
          C[(((size_t)(bb*F_ + f))*CEXP + n)*HW + hw] = v;
        }
      }
    }
  }
}

// ---------------- fused conv1d + SSD + gate + RMSNorm, one block per sequence ----------------
__global__ __launch_bounds__(256,1) void ssm_kernel(
    const float* __restrict__ Zc,      // (SEQ_PER, F_, D_IN_PROJ)
    const float* __restrict__ conv_w,  // (CONV_DIM, 4)
    const float* __restrict__ conv_b,  // (CONV_DIM)
    const float* __restrict__ dt_bias, // (NHEADS)
    const float* __restrict__ A_log,   // (NHEADS)
    const float* __restrict__ Dp,      // (NHEADS)
    const float* __restrict__ rms_w,   // (D_INNER)
    __hip_bfloat16* __restrict__ Yc)   // (SEQ_PER, F_, D_INNER) bf16
{
  __shared__ float xbc[F_][CONV_DIM];          // 80 KiB
  __shared__ float wts[F_][F_][NHEADS];        // 16 KiB
  __shared__ float dts[F_][NHEADS];
  __shared__ float cums[F_][NHEADS];
  __shared__ float scor[F_][F_];
  __shared__ float red[256];
  __shared__ float rinv[F_];
  const int tid = threadIdx.x;
  const float* Zb = Zc + (size_t)blockIdx.x * F_ * D_IN_PROJ;
  __hip_bfloat16* Yb = Yc + (size_t)blockIdx.x * F_ * D_INNER;

  {
    int t = tid >> 4, h = tid & 15;
    float v = Zb[t*D_IN_PROJ + (D_INNER + CONV_DIM) + h] + dt_bias[h];
    dts[t][h] = (v > 20.f) ? v : log1pf(expf(v));
  }
  __syncthreads();
  if (tid < NHEADS){
    float A = -expf(A_log[tid]);
    float c = 0.f;
    for (int t = 0; t < F_; t++){ c += dts[t][tid]*A; cums[t][tid] = c; }
  }
  for (int i = tid; i < F_*CONV_DIM; i += 256){
    int t = i / CONV_DIM, c = i - t*CONV_DIM;
    float acc = conv_b[c];
    #pragma unroll
    for (int k = 0; k < D_CONV; k++){
      int s = t + k - (D_CONV-1);
      if (s >= 0) acc += Zb[s*D_IN_PROJ + D_INNER + c] * conv_w[c*D_CONV + k];
    }
    xbc[t][c] = acc / (1.f + expf(-acc));
  }
  __syncthreads();
  {
    int t = tid >> 4, s = tid & 15;
    float acc = 0.f;
    for (int n = 0; n < D_STATE; n++)
      acc += xbc[t][D_INNER + D_STATE + n] * xbc[s][D_INNER + n];
    scor[t][s] = acc;
  }
  __syncthreads();
  for (int i = tid; i < F_*F_*NHEADS; i += 256){
    int h = i & 15, s = (i >> 4) & 15, t = i >> 8;
    float v = 0.f;
    if (s <= t) v = scor[t][s] * expf(cums[t][h] - cums[s][h]) * dts[s][h];
    wts[t][s][h] = v;
  }
  __syncthreads();
  for (int rep = 0; rep < D_INNER/256; rep++){
    int col = rep*256 + tid;
    int h = col >> 6;
    float Dh = Dp[h];
    float y[F_];
    #pragma unroll
    for (int t = 0; t < F_; t++){
      float acc = Dh * xbc[t][col];
      #pragma unroll
      for (int s = 0; s <= t; s++)
        acc += wts[t][s][h] * xbc[s][col];
      y[t] = acc;
    }
    #pragma unroll
    for (int t = 0; t < F_; t++){
      float z = Zb[t*D_IN_PROJ + col];
      float sg = 1.f / (1.f + expf(-z));
      xbc[t][col] = y[t] * z * sg;
    }
  }
  __syncthreads();
  {
    int t = tid >> 4, seg = tid & 15;
    float s = 0.f;
    for (int c = seg*64; c < seg*64 + 64; c++){ float v = xbc[t][c]; s += v*v; }
    red[tid] = s;
  }
  __syncthreads();
  if (tid < F_){
    float s = 0.f;
    for (int j = 0; j < 16; j++) s += red[tid*16 + j];
    rinv[tid] = rsqrtf(s / D_INNER + 1e-5f);
  }
  __syncthreads();
  for (int i = tid; i < F_*D_INNER; i += 256){
    int t = i >> 10, c = i & (D_INNER-1);
    Yb[i] = __float2bfloat16(xbc[t][c] * rinv[t] * rms_w[c]);
  }
}

// ---------------- launcher ----------------
// workspace (float offsets), ~160 MiB peak:
//   A    f32 [0,        10485760)  GN out            } dead after step2/3;
//   Bp   f32 [10485760, 20971520)  proj_in out       } region reused as R (16,777,216 f)
//   Ub  bf16 [20971520, 29360128)  U sequences bf16 (32 MiB)   } dead after chunk loop;
//   Wb  bf16 [29360128, 29982720)  in_proj_w bf16 padded       } region reused as Cc
//   Wob bf16 [29982720, 30244864)  out_proj_w bf16             }   (10,485,760 f)
//   Z    f32 [30244864, 39747584)  zxbcdt chunk
//   Ycb bf16 [39747584, 41844736)  ssm out chunk bf16
extern "C" void kernel_launch(void* const* d_in, const int* in_sizes, int n_in,
                              void* d_out, int out_size, void* d_ws, size_t ws_size,
                              hipStream_t stream)
{
  const float* x         = (const float*)d_in[0];
  const float* norm_w    = (const float*)d_in[1];
  const float* norm_b    = (const float*)d_in[2];
  const float* proj_in_w = (const float*)d_in[3];
  const float* proj_in_b = (const float*)d_in[4];
  const float* expand_w  = (const float*)d_in[5];
  const float* expand_b  = (const float*)d_in[6];
  const float* in_proj_w = (const float*)d_in[7];
  const float* conv_w    = (const float*)d_in[8];
  const float* conv_b    = (const float*)d_in[9];
  const float* dt_bias   = (const float*)d_in[10];
  const float* A_log     = (const float*)d_in[11];
  const float* Dvec      = (const float*)d_in[12];
  const float* rms_w     = (const float*)d_in[13];
  const float* out_proj_w= (const float*)d_in[14];
  const float* collapse_w= (const float*)d_in[15];
  const float* collapse_b= (const float*)d_in[16];
  const float* proj_out_w= (const float*)d_in[17];
  const float* proj_out_b= (const float*)d_in[18];
  const float* gamma     = (const float*)d_in[19];
  float* out = (float*)d_out;

  float* WS = (float*)d_ws;
  float*          A   = WS;
  float*          Bp  = WS + 10485760;
  float*          R   = WS;                                   // frames f32, reuses A+Bp
  __hip_bfloat16* Ub  = (__hip_bfloat16*)(WS + 20971520);
  __hip_bfloat16* Wb  = (__hip_bfloat16*)(WS + 29360128);
  __hip_bfloat16* Wob = (__hip_bfloat16*)(WS + 29982720);
  float*          Cc  = WS + 20971520;                        // collapse out, reuses Ub..Z
  float*          Z   = WS + 30244864;
  __hip_bfloat16* Ycb = (__hip_bfloat16*)(WS + 39747584);

  // 0) weight conversions (bf16)
  cvt_pad_kernel<<<(NPAD*CEXP + 255)/256, 256, 0, stream>>>(in_proj_w, Wb, D_IN_PROJ, NPAD, CEXP);
  cvt_pad_kernel<<<(CEXP*D_INNER + 255)/256, 256, 0, stream>>>(out_proj_w, Wob, CEXP, CEXP, D_INNER);
  // 1) GroupNorm: x -> A
  gn_kernel<<<dim3(GROUPS, NB), 256, 0, stream>>>(x, norm_w, norm_b, A);
  // 2) proj_in (320->320): A -> Bp
  gemm_nn_kernel<<<dim3(HW/64, C0/64, NB), 256, 0, stream>>>(
      proj_in_w, A, proj_in_b, Bp, C0, HW, C0, nullptr, nullptr);
  // 3) expand (320->512) fused frames->seq, bf16: Bp -> Ub
  gemm_nn_seq_kernel<<<dim3(HW/64, CEXP/64, NB), 256, 0, stream>>>(
      expand_w, Bp, expand_b, Ub, CEXP, HW, C0);
  // 4) chunked: in_proj MFMA -> ssm -> out_proj MFMA (fused seq->frames) into R
  for (int c = 0; c < NCHUNK; c++){
    const __hip_bfloat16* Uc = Ub + (size_t)c*TOK_PER*CEXP;
    mfma_nt_kernel<0><<<dim3(NPAD/128, TOK_PER/128), 256, 0, stream>>>(
        Uc, Wb, Z, TOK_PER, D_IN_PROJ, CEXP, 0);
    ssm_kernel<<<SEQ_PER, 256, 0, stream>>>(
        Z, conv_w, conv_b, dt_bias, A_log, Dvec, rms_w, Ycb);
    mfma_nt_kernel<1><<<dim3(CEXP/128, TOK_PER/128), 256, 0, stream>>>(
        Ycb, Wob, R, TOK_PER, CEXP, D_INNER, c*SEQ_PER);
  }
  // 5) collapse (512->320): R -> Cc
  gemm_nn_kernel<<<dim3(HW/64, C0/64, NB), 256, 0, stream>>>(
      collapse_w, R, collapse_b, Cc, C0, HW, CEXP, nullptr, nullptr);
  // 6) proj_out (320->320) + residual: Cc -> out
  gemm_nn_kernel<<<dim3(HW/64, C0/64, NB), 256, 0, stream>>>(
      proj_out_w, Cc, proj_out_b, out, C0, HW, C0, x, gamma);
}

// Round 5
// 1638.840 us; speedup vs baseline: 2.6077x; 1.4101x over previous
//
#include <hip/hip_runtime.h>
#include <hip/hip_bf16.h>

// ---------------- problem constants ----------------
#define B_ 2
#define F_ 16
#define Hs 32
#define Ws 32
#define C0 320
#define CEXP 512
#define D_INNER 1024
#define NHEADS 16
#define HEADDIM 64
#define D_STATE 128
#define D_CONV 4
#define CONV_DIM (D_INNER + 2*D_STATE)              // 1280
#define D_IN_PROJ (2*D_INNER + 2*D_STATE + NHEADS)  // 2320
#define NPAD 2432                                   // 19*128 padded in_proj rows
#define C0PAD 384                                   // 3*128 padded 320-row weights
#define GROUPS 32
#define NB (B_*F_)        // 32 frames
#define HW (Hs*Ws)        // 1024 spatial
#define NSEQ (B_*HW)      // 2048 sequences
#define NTOK (NSEQ*F_)    // 32768 tokens
#define NCHUNK 8
#define SEQ_PER (NSEQ/NCHUNK)   // 256
#define TOK_PER (SEQ_PER*F_)    // 4096

typedef __bf16 bf16x8 __attribute__((ext_vector_type(8)));
typedef float f32x4 __attribute__((ext_vector_type(4)));

// ---------------- GroupNorm (f32 frames) ----------------
__global__ __launch_bounds__(256) void gn_kernel(const float* __restrict__ x,
    const float* __restrict__ w, const float* __restrict__ b, float* __restrict__ out)
{
  const int CG = C0/GROUPS;            // 10
  const int NEL = CG*HW;               // 10240
  int g = blockIdx.x, n = blockIdx.y;
  const float* xp = x + ((size_t)n*C0 + (size_t)g*CG)*HW;
  float* op = out + ((size_t)n*C0 + (size_t)g*CG)*HW;
  float s = 0.f, ss = 0.f;
  for (int i = threadIdx.x; i < NEL; i += 256){ float v = xp[i]; s += v; ss += v*v; }
  __shared__ float rs[256], rq[256];
  rs[threadIdx.x] = s; rq[threadIdx.x] = ss;
  __syncthreads();
  for (int o = 128; o > 0; o >>= 1){
    if (threadIdx.x < o){ rs[threadIdx.x] += rs[threadIdx.x+o]; rq[threadIdx.x] += rq[threadIdx.x+o]; }
    __syncthreads();
  }
  float mu  = rs[0] / NEL;
  float var = rq[0] / NEL - mu*mu;
  float inv = rsqrtf(var + 1e-5f);
  for (int i = threadIdx.x; i < NEL; i += 256){
    int c = g*CG + i/HW;
    op[i] = (xp[i] - mu)*inv*w[c] + b[c];
  }
}

// ---------------- weight f32 -> bf16 conversion (optional row padding) ----------------
__global__ __launch_bounds__(256) void cvt_pad_kernel(const float* __restrict__ w,
    __hip_bfloat16* __restrict__ o, int Nreal, int Npad, int K)
{
  int i = blockIdx.x*256 + threadIdx.x;
  if (i >= Npad*K) return;
  int n = i / K;
  int k = i - n*K;
  float v = (n < Nreal) ? w[(size_t)n*K + k] : 0.f;
  o[i] = __float2bfloat16(v);
}

// ---------------- frames f32 (n,c,hw) -> token-major bf16 (n*HW+hw, c) ----------------
__global__ __launch_bounds__(256) void tok_cvt_kernel(const float* __restrict__ Xg,
    __hip_bfloat16* __restrict__ X0)
{
  __shared__ float t[64][65];
  const int n = blockIdx.z, c0 = blockIdx.y*64, hw0 = blockIdx.x*64;
  const int r = threadIdx.x >> 2, sl = threadIdx.x & 3;
  size_t ibase = ((size_t)n*C0 + c0 + r)*HW + hw0 + sl*16;
  #pragma unroll
  for (int j = 0; j < 16; j++) t[r][sl*16 + j] = Xg[ibase + j];   // t[c_local][hw_local]
  __syncthreads();
  __hip_bfloat16* Orow = X0 + ((size_t)(n*HW + hw0 + r))*C0 + c0 + sl*16;
  union { uint4 u; __hip_bfloat16 h[8]; } v;
  #pragma unroll
  for (int half = 0; half < 2; half++){
    #pragma unroll
    for (int j = 0; j < 8; j++) v.h[j] = __float2bfloat16(t[sl*16 + half*8 + j][r]);
    *(uint4*)(Orow + half*8) = v.u;
  }
}

// ---------------- final: P bf16 tokens -> out f32 frames with residual ----------------
__global__ __launch_bounds__(256) void final_kernel(const __hip_bfloat16* __restrict__ P,
    const float* __restrict__ x, const float* __restrict__ gammap, float* __restrict__ out)
{
  __shared__ float t[64][65];
  const int n = blockIdx.z, c0 = blockIdx.y*64, hw0 = blockIdx.x*64;
  const int r = threadIdx.x >> 2, sl = threadIdx.x & 3;
  const __hip_bfloat16* Pr = P + ((size_t)(n*HW + hw0 + r))*C0 + c0 + sl*16;
  union { uint4 u; __hip_bfloat16 h[8]; } v;
  #pragma unroll
  for (int half = 0; half < 2; half++){
    v.u = *(const uint4*)(Pr + half*8);
    #pragma unroll
    for (int j = 0; j < 8; j++) t[sl*16 + half*8 + j][r] = __bfloat162float(v.h[j]);
  }
  __syncthreads();
  const float g = *gammap;
  size_t obase = ((size_t)n*C0 + c0 + r)*HW + hw0 + sl*16;
  #pragma unroll
  for (int j = 0; j < 16; j++)
    out[obase + j] = x[obase + j] + g*t[r][sl*16 + j];
}

// ---------------- bf16 MFMA GEMM NT: O = A(MxK) * Bw(NpadxK)^T (+bias[n]) ----------------
// 128x128 tile, BK=32, 4 waves (2x2), each wave 64x64 via 4x4 16x16x32 mfma frags.
// LDS [128 rows][32 k] bf16, 16B-granule XOR swizzle: slot ^= (row>>1)&3.
// MODE 0: f32 out, O[m*Nreal+n], guard n<Nreal              (in_proj -> Z)
// MODE 1: bf16 out +bias, O[m*Nreal+n], guard n<Nreal       (proj_in, collapse, proj_out)
// MODE 2: bf16 out +bias, frame-tok -> seq-tok row permute  (expand -> U)
// MODE 3: bf16 out, seq-tok -> frame-tok row permute        (out_proj -> V)
template<int MODE>
__global__ __launch_bounds__(256) void mfma_nt_kernel(
    const __hip_bfloat16* __restrict__ A,   // M x K
    const __hip_bfloat16* __restrict__ Bw,  // Npad x K
    void* __restrict__ Optr,
    int Nreal, int K, int c0tok,
    const float* __restrict__ bias)
{
  __shared__ unsigned short As[128*32];
  __shared__ unsigned short Bs[128*32];
  const int tid = threadIdx.x;
  const int lane = tid & 63;
  const int m0 = blockIdx.y * 128;
  const int n0 = blockIdx.x * 128;

  const int row0 = tid >> 2;
  const int sl   = tid & 3;
  const int row1 = row0 + 64;
  const int sw0  = sl ^ ((row0 >> 1) & 3);
  const int sw1  = sl ^ ((row1 >> 1) & 3);
  const size_t Aoff0 = (size_t)(m0 + row0)*K + sl*8;
  const size_t Aoff1 = (size_t)(m0 + row1)*K + sl*8;
  const size_t Boff0 = (size_t)(n0 + row0)*K + sl*8;
  const size_t Boff1 = (size_t)(n0 + row1)*K + sl*8;
  const int wp0 = row0*32 + sw0*8;
  const int wp1 = row1*32 + sw1*8;

  const int wid = tid >> 6, wr = wid >> 1, wc = wid & 1;
  const int fr = lane & 15, ks = lane >> 4;
  int aoff[4], boff[4];
  #pragma unroll
  for (int i = 0; i < 4; i++){
    int ra = wr*64 + i*16 + fr;
    aoff[i] = ra*32 + ((ks ^ ((ra>>1)&3))<<3);
    int rb = wc*64 + i*16 + fr;
    boff[i] = rb*32 + ((ks ^ ((rb>>1)&3))<<3);
  }

  f32x4 acc[4][4];
  #pragma unroll
  for (int mi = 0; mi < 4; mi++)
    #pragma unroll
    for (int ni = 0; ni < 4; ni++)
      acc[mi][ni] = (f32x4)(0.f);

  for (int k0 = 0; k0 < K; k0 += 32){
    uint4 a0 = *(const uint4*)(A  + Aoff0 + k0);
    uint4 a1 = *(const uint4*)(A  + Aoff1 + k0);
    uint4 b0 = *(const uint4*)(Bw + Boff0 + k0);
    uint4 b1 = *(const uint4*)(Bw + Boff1 + k0);
    __syncthreads();
    *(uint4*)&As[wp0] = a0;
    *(uint4*)&As[wp1] = a1;
    *(uint4*)&Bs[wp0] = b0;
    *(uint4*)&Bs[wp1] = b1;
    __syncthreads();
    bf16x8 af[4], bfv[4];
    #pragma unroll
    for (int i = 0; i < 4; i++){
      af[i]  = *(const bf16x8*)&As[aoff[i]];
      bfv[i] = *(const bf16x8*)&Bs[boff[i]];
    }
    #pragma unroll
    for (int mi = 0; mi < 4; mi++)
      #pragma unroll
      for (int ni = 0; ni < 4; ni++)
        acc[mi][ni] = __builtin_amdgcn_mfma_f32_16x16x32_bf16(af[mi], bfv[ni], acc[mi][ni], 0, 0, 0);
  }

  #pragma unroll
  for (int mi = 0; mi < 4; mi++){
    #pragma unroll
    for (int ni = 0; ni < 4; ni++){
      #pragma unroll
      for (int i = 0; i < 4; i++){
        int m = m0 + wr*64 + mi*16 + (lane>>4)*4 + i;   // C/D: row=(lane>>4)*4+reg
        int n = n0 + wc*64 + ni*16 + (lane&15);          //      col=lane&15
        if (n >= Nreal) continue;
        float v = acc[mi][ni][i];
        if (MODE == 0){
          ((float*)Optr)[(size_t)m*Nreal + n] = v;
        } else if (MODE == 1){
          ((__hip_bfloat16*)Optr)[(size_t)m*Nreal + n] = __float2bfloat16(v + bias[n]);
        } else if (MODE == 2){
          int nf = m >> 10, hw = m & (HW-1);
          int bb = nf >> 4, f = nf & (F_-1);
          size_t urow = ((size_t)((bb << 10) | hw))*F_ + f;
          ((__hip_bfloat16*)Optr)[urow*CEXP + n] = __float2bfloat16(v + bias[n]);
        } else {
          int st = c0tok + m;
          int sq = st >> 4, f = st & (F_-1);
          int bb = sq >> 10, hw = sq & (HW-1);
          size_t vrow = ((size_t)((bb << 4) | f))*HW + hw;
          ((__hip_bfloat16*)Optr)[vrow*CEXP + n] = __float2bfloat16(v);
        }
      }
    }
  }
}

// ---------------- fused conv1d + SSD + gate + RMSNorm, one block per sequence ----------------
__global__ __launch_bounds__(256,1) void ssm_kernel(
    const float* __restrict__ Zc,      // (SEQ_PER, F_, D_IN_PROJ)
    const float* __restrict__ conv_w,  // (CONV_DIM, 4)
    const float* __restrict__ conv_b,  // (CONV_DIM)
    const float* __restrict__ dt_bias, // (NHEADS)
    const float* __restrict__ A_log,   // (NHEADS)
    const float* __restrict__ Dp,      // (NHEADS)
    const float* __restrict__ rms_w,   // (D_INNER)
    __hip_bfloat16* __restrict__ Yc)   // (SEQ_PER, F_, D_INNER) bf16
{
  __shared__ float xbc[F_][CONV_DIM+1];        // +1 pad: kills 16-way conflict in scores loop
  __shared__ float wts[F_][F_][NHEADS];
  __shared__ float dts[F_][NHEADS];
  __shared__ float cums[F_][NHEADS];
  __shared__ float scor[F_][F_];
  __shared__ float red[256];
  __shared__ float rinv[F_];
  const int tid = threadIdx.x;
  const float* Zb = Zc + (size_t)blockIdx.x * F_ * D_IN_PROJ;
  __hip_bfloat16* Yb = Yc + (size_t)blockIdx.x * F_ * D_INNER;

  {
    int t = tid >> 4, h = tid & 15;
    float v = Zb[t*D_IN_PROJ + (D_INNER + CONV_DIM) + h] + dt_bias[h];
    dts[t][h] = (v > 20.f) ? v : log1pf(expf(v));
  }
  __syncthreads();
  if (tid < NHEADS){
    float A = -expf(A_log[tid]);
    float c = 0.f;
    for (int t = 0; t < F_; t++){ c += dts[t][tid]*A; cums[t][tid] = c; }
  }
  for (int i = tid; i < F_*CONV_DIM; i += 256){
    int t = i / CONV_DIM, c = i - t*CONV_DIM;
    float acc = conv_b[c];
    #pragma unroll
    for (int k = 0; k < D_CONV; k++){
      int s = t + k - (D_CONV-1);
      if (s >= 0) acc += Zb[s*D_IN_PROJ + D_INNER + c] * conv_w[c*D_CONV + k];
    }
    xbc[t][c] = acc / (1.f + expf(-acc));
  }
  __syncthreads();
  {
    int t = tid >> 4, s = tid & 15;
    float acc = 0.f;
    for (int n = 0; n < D_STATE; n++)
      acc += xbc[t][D_INNER + D_STATE + n] * xbc[s][D_INNER + n];
    scor[t][s] = acc;
  }
  __syncthreads();
  for (int i = tid; i < F_*F_*NHEADS; i += 256){
    int h = i & 15, s = (i >> 4) & 15, t = i >> 8;
    float v = 0.f;
    if (s <= t) v = scor[t][s] * expf(cums[t][h] - cums[s][h]) * dts[s][h];
    wts[t][s][h] = v;
  }
  __syncthreads();
  for (int rep = 0; rep < D_INNER/256; rep++){
    int col = rep*256 + tid;
    int h = col >> 6;                   // wave-uniform
    float Dh = Dp[h];
    float xr[F_];
    #pragma unroll
    for (int t = 0; t < F_; t++) xr[t] = xbc[t][col];
    float y[F_];
    #pragma unroll
    for (int t = 0; t < F_; t++){
      float acc = Dh * xr[t];
      #pragma unroll
      for (int s = 0; s <= t; s++)
        acc += wts[t][s][h] * xr[s];    // wts read is wave-broadcast
      y[t] = acc;
    }
    #pragma unroll
    for (int t = 0; t < F_; t++){
      float z = Zb[t*D_IN_PROJ + col];
      float sg = 1.f / (1.f + expf(-z));
      xbc[t][col] = y[t] * z * sg;
    }
  }
  __syncthreads();
  {
    int t = tid >> 4, seg = tid & 15;
    float s = 0.f;
    for (int c = seg*64; c < seg*64 + 64; c++){ float v = xbc[t][c]; s += v*v; }
    red[tid] = s;
  }
  __syncthreads();
  if (tid < F_){
    float s = 0.f;
    for (int j = 0; j < 16; j++) s += red[tid*16 + j];
    rinv[tid] = rsqrtf(s / D_INNER + 1e-5f);
  }
  __syncthreads();
  for (int i = tid; i < F_*D_INNER; i += 256){
    int t = i >> 10, c = i & (D_INNER-1);
    Yb[i] = __float2bfloat16(xbc[t][c] * rinv[t] * rms_w[c]);
  }
}

// ---------------- launcher ----------------
// workspace (float offsets), peak ~169 MiB (see layout in analysis)
extern "C" void kernel_launch(void* const* d_in, const int* in_sizes, int n_in,
                              void* d_out, int out_size, void* d_ws, size_t ws_size,
                              hipStream_t stream)
{
  const float* x         = (const float*)d_in[0];
  const float* norm_w    = (const float*)d_in[1];
  const float* norm_b    = (const float*)d_in[2];
  const float* proj_in_w = (const float*)d_in[3];
  const float* proj_in_b = (const float*)d_in[4];
  const float* expand_w  = (const float*)d_in[5];
  const float* expand_b  = (const float*)d_in[6];
  const float* in_proj_w = (const float*)d_in[7];
  const float* conv_w    = (const float*)d_in[8];
  const float* conv_b    = (const float*)d_in[9];
  const float* dt_bias   = (const float*)d_in[10];
  const float* A_log     = (const float*)d_in[11];
  const float* Dvec      = (const float*)d_in[12];
  const float* rms_w     = (const float*)d_in[13];
  const float* out_proj_w= (const float*)d_in[14];
  const float* collapse_w= (const float*)d_in[15];
  const float* collapse_b= (const float*)d_in[16];
  const float* proj_out_w= (const float*)d_in[17];
  const float* proj_out_b= (const float*)d_in[18];
  const float* gamma     = (const float*)d_in[19];
  float* out = (float*)d_out;

  float* WS = (float*)d_ws;
  float*          Xg  = WS;
  __hip_bfloat16* V   = (__hip_bfloat16*)WS;                   // reuses Xg
  __hip_bfloat16* X0  = (__hip_bfloat16*)(WS + 10485760);
  __hip_bfloat16* C2  = (__hip_bfloat16*)(WS + 10485760);      // reuses X0
  __hip_bfloat16* X1  = (__hip_bfloat16*)(WS + 15728640);
  __hip_bfloat16* P   = (__hip_bfloat16*)(WS + 15728640);      // reuses X1
  __hip_bfloat16* U   = (__hip_bfloat16*)(WS + 20971520);
  __hip_bfloat16* Wb  = (__hip_bfloat16*)(WS + 29360128);
  __hip_bfloat16* Wob = (__hip_bfloat16*)(WS + 29982720);
  __hip_bfloat16* Wpb = (__hip_bfloat16*)(WS + 30244864);
  __hip_bfloat16* Web = (__hip_bfloat16*)(WS + 30306304);
  __hip_bfloat16* Wcb = (__hip_bfloat16*)(WS + 30388224);
  __hip_bfloat16* Wqb = (__hip_bfloat16*)(WS + 30486528);
  float*          Z   = WS + 30547968;
  __hip_bfloat16* Ycb = (__hip_bfloat16*)(WS + 40050688);

  // 0) weight conversions
  cvt_pad_kernel<<<(NPAD*CEXP+255)/256, 256, 0, stream>>>(in_proj_w, Wb, D_IN_PROJ, NPAD, CEXP);
  cvt_pad_kernel<<<(CEXP*D_INNER+255)/256, 256, 0, stream>>>(out_proj_w, Wob, CEXP, CEXP, D_INNER);
  cvt_pad_kernel<<<(C0PAD*C0+255)/256, 256, 0, stream>>>(proj_in_w, Wpb, C0, C0PAD, C0);
  cvt_pad_kernel<<<(CEXP*C0+255)/256, 256, 0, stream>>>(expand_w, Web, CEXP, CEXP, C0);
  cvt_pad_kernel<<<(C0PAD*CEXP+255)/256, 256, 0, stream>>>(collapse_w, Wcb, C0, C0PAD, CEXP);
  cvt_pad_kernel<<<(C0PAD*C0+255)/256, 256, 0, stream>>>(proj_out_w, Wqb, C0, C0PAD, C0);
  // 1) GroupNorm
  gn_kernel<<<dim3(GROUPS, NB), 256, 0, stream>>>(x, norm_w, norm_b, Xg);
  // 2) frames -> token-major bf16
  tok_cvt_kernel<<<dim3(HW/64, C0/64, NB), 256, 0, stream>>>(Xg, X0);
  // 3) proj_in
  mfma_nt_kernel<1><<<dim3(C0PAD/128, NTOK/128), 256, 0, stream>>>(
      X0, Wpb, X1, C0, C0, 0, proj_in_b);
  // 4) expand, rows permuted frame->seq
  mfma_nt_kernel<2><<<dim3(CEXP/128, NTOK/128), 256, 0, stream>>>(
      X1, Web, U, CEXP, C0, 0, expand_b);
  // 5) chunked mamba
  for (int c = 0; c < NCHUNK; c++){
    const __hip_bfloat16* Uc = U + (size_t)c*TOK_PER*CEXP;
    mfma_nt_kernel<0><<<dim3(NPAD/128, TOK_PER/128), 256, 0, stream>>>(
        Uc, Wb, Z, D_IN_PROJ, CEXP, 0, nullptr);
    ssm_kernel<<<SEQ_PER, 256, 0, stream>>>(
        Z, conv_w, conv_b, dt_bias, A_log, Dvec, rms_w, Ycb);
    mfma_nt_kernel<3><<<dim3(CEXP/128, TOK_PER/128), 256, 0, stream>>>(
        Ycb, Wob, V, CEXP, D_INNER, c*TOK_PER, nullptr);
  }
  // 6) collapse (+bias)
  mfma_nt_kernel<1><<<dim3(C0PAD/128, NTOK/128), 256, 0, stream>>>(
      V, Wcb, C2, C0, CEXP, 0, collapse_b);
  // 7) proj_out (+bias)
  mfma_nt_kernel<1><<<dim3(C0PAD/128, NTOK/128), 256, 0, stream>>>(
      C2, Wqb, P, C0, C0, 0, proj_out_b);
  // 8) final residual transpose: out = x + gamma * P
  final_kernel<<<dim3(HW/64, C0/64, NB), 256, 0, stream>>>(P, x, gamma, out);
}

// Round 6
// 826.220 us; speedup vs baseline: 5.1726x; 1.9835x over previous
//
#include <hip/hip_runtime.h>
#include <hip/hip_bf16.h>

// ---------------- problem constants ----------------
#define B_ 2
#define F_ 16
#define Hs 32
#define Ws 32
#define C0 320
#define CEXP 512
#define D_INNER 1024
#define NHEADS 16
#define HEADDIM 64
#define D_STATE 128
#define D_CONV 4
#define CONV_DIM (D_INNER + 2*D_STATE)              // 1280
#define D_IN_PROJ (2*D_INNER + 2*D_STATE + NHEADS)  // 2320
#define NPAD 2432                                   // 19*128 padded in_proj rows
#define C0PAD 384                                   // 3*128 padded 320-row weights
#define GROUPS 32
#define NB (B_*F_)        // 32 frames
#define HW (Hs*Ws)        // 1024 spatial
#define NSEQ (B_*HW)      // 2048 sequences
#define NTOK (NSEQ*F_)    // 32768 tokens
#define NCHUNK 4
#define SEQ_PER (NSEQ/NCHUNK)   // 512
#define TOK_PER (SEQ_PER*F_)    // 8192

typedef __bf16 bf16x8 __attribute__((ext_vector_type(8)));
typedef float f32x4 __attribute__((ext_vector_type(4)));

// ---------------- GroupNorm (f32 frames) ----------------
__global__ __launch_bounds__(256) void gn_kernel(const float* __restrict__ x,
    const float* __restrict__ w, const float* __restrict__ b, float* __restrict__ out)
{
  const int CG = C0/GROUPS;            // 10
  const int NEL = CG*HW;               // 10240
  int g = blockIdx.x, n = blockIdx.y;
  const float* xp = x + ((size_t)n*C0 + (size_t)g*CG)*HW;
  float* op = out + ((size_t)n*C0 + (size_t)g*CG)*HW;
  float s = 0.f, ss = 0.f;
  for (int i = threadIdx.x; i < NEL; i += 256){ float v = xp[i]; s += v; ss += v*v; }
  __shared__ float rs[256], rq[256];
  rs[threadIdx.x] = s; rq[threadIdx.x] = ss;
  __syncthreads();
  for (int o = 128; o > 0; o >>= 1){
    if (threadIdx.x < o){ rs[threadIdx.x] += rs[threadIdx.x+o]; rq[threadIdx.x] += rq[threadIdx.x+o]; }
    __syncthreads();
  }
  float mu  = rs[0] / NEL;
  float var = rq[0] / NEL - mu*mu;
  float inv = rsqrtf(var + 1e-5f);
  for (int i = threadIdx.x; i < NEL; i += 256){
    int c = g*CG + i/HW;
    op[i] = (xp[i] - mu)*inv*w[c] + b[c];
  }
}

// ---------------- weight f32 -> bf16 conversion (optional row padding) ----------------
__global__ __launch_bounds__(256) void cvt_pad_kernel(const float* __restrict__ w,
    __hip_bfloat16* __restrict__ o, int Nreal, int Npad, int K)
{
  int i = blockIdx.x*256 + threadIdx.x;
  if (i >= Npad*K) return;
  int n = i / K;
  int k = i - n*K;
  float v = (n < Nreal) ? w[(size_t)n*K + k] : 0.f;
  o[i] = __float2bfloat16(v);
}

// ---------------- frames f32 (n,c,hw) -> token-major bf16 (n*HW+hw, c) ----------------
__global__ __launch_bounds__(256) void tok_cvt_kernel(const float* __restrict__ Xg,
    __hip_bfloat16* __restrict__ X0)
{
  __shared__ float t[64][65];
  const int n = blockIdx.z, c0 = blockIdx.y*64, hw0 = blockIdx.x*64;
  const int r = threadIdx.x >> 2, sl = threadIdx.x & 3;
  size_t ibase = ((size_t)n*C0 + c0 + r)*HW + hw0 + sl*16;
  #pragma unroll
  for (int j = 0; j < 16; j++) t[r][sl*16 + j] = Xg[ibase + j];   // t[c_local][hw_local]
  __syncthreads();
  __hip_bfloat16* Orow = X0 + ((size_t)(n*HW + hw0 + r))*C0 + c0 + sl*16;
  union { uint4 u; __hip_bfloat16 h[8]; } v;
  #pragma unroll
  for (int half = 0; half < 2; half++){
    #pragma unroll
    for (int j = 0; j < 8; j++) v.h[j] = __float2bfloat16(t[sl*16 + half*8 + j][r]);
    *(uint4*)(Orow + half*8) = v.u;
  }
}

// ---------------- final: P bf16 tokens -> out f32 frames with residual ----------------
__global__ __launch_bounds__(256) void final_kernel(const __hip_bfloat16* __restrict__ P,
    const float* __restrict__ x, const float* __restrict__ gammap, float* __restrict__ out)
{
  __shared__ float t[64][65];
  const int n = blockIdx.z, c0 = blockIdx.y*64, hw0 = blockIdx.x*64;
  const int r = threadIdx.x >> 2, sl = threadIdx.x & 3;
  const __hip_bfloat16* Pr = P + ((size_t)(n*HW + hw0 + r))*C0 + c0 + sl*16;
  union { uint4 u; __hip_bfloat16 h[8]; } v;
  #pragma unroll
  for (int half = 0; half < 2; half++){
    v.u = *(const uint4*)(Pr + half*8);
    #pragma unroll
    for (int j = 0; j < 8; j++) t[sl*16 + half*8 + j][r] = __bfloat162float(v.h[j]);
  }
  __syncthreads();
  const float g = *gammap;
  size_t obase = ((size_t)n*C0 + c0 + r)*HW + hw0 + sl*16;
  #pragma unroll
  for (int j = 0; j < 16; j++)
    out[obase + j] = x[obase + j] + g*t[r][sl*16 + j];
}

// ---------------- bf16 MFMA GEMM NT: O = A(MxK) * Bw(NpadxK)^T (+bias[n]) ----------------
// 128x128 tile, BK=32, 4 waves (2x2), each wave 64x64 via 4x4 16x16x32 mfma frags.
// LDS [128 rows][32 k] bf16, 16B-granule XOR swizzle: slot ^= (row>>1)&3.
// MODE 0: bf16 out (no bias), O[m*Nreal+n], guard n<Nreal   (in_proj -> Z)
// MODE 1: bf16 out +bias, O[m*Nreal+n], guard n<Nreal       (proj_in, collapse, proj_out)
// MODE 2: bf16 out +bias, frame-tok -> seq-tok row permute  (expand -> U)
// MODE 3: bf16 out, seq-tok -> frame-tok row permute        (out_proj -> V)
template<int MODE>
__global__ __launch_bounds__(256) void mfma_nt_kernel(
    const __hip_bfloat16* __restrict__ A,   // M x K
    const __hip_bfloat16* __restrict__ Bw,  // Npad x K
    void* __restrict__ Optr,
    int Nreal, int K, int c0tok,
    const float* __restrict__ bias)
{
  __shared__ unsigned short As[128*32];
  __shared__ unsigned short Bs[128*32];
  const int tid = threadIdx.x;
  const int lane = tid & 63;
  const int m0 = blockIdx.y * 128;
  const int n0 = blockIdx.x * 128;

  const int row0 = tid >> 2;
  const int sl   = tid & 3;
  const int row1 = row0 + 64;
  const int sw0  = sl ^ ((row0 >> 1) & 3);
  const int sw1  = sl ^ ((row1 >> 1) & 3);
  const size_t Aoff0 = (size_t)(m0 + row0)*K + sl*8;
  const size_t Aoff1 = (size_t)(m0 + row1)*K + sl*8;
  const size_t Boff0 = (size_t)(n0 + row0)*K + sl*8;
  const size_t Boff1 = (size_t)(n0 + row1)*K + sl*8;
  const int wp0 = row0*32 + sw0*8;
  const int wp1 = row1*32 + sw1*8;

  const int wid = tid >> 6, wr = wid >> 1, wc = wid & 1;
  const int fr = lane & 15, ks = lane >> 4;
  int aoff[4], boff[4];
  #pragma unroll
  for (int i = 0; i < 4; i++){
    int ra = wr*64 + i*16 + fr;
    aoff[i] = ra*32 + ((ks ^ ((ra>>1)&3))<<3);
    int rb = wc*64 + i*16 + fr;
    boff[i] = rb*32 + ((ks ^ ((rb>>1)&3))<<3);
  }

  f32x4 acc[4][4];
  #pragma unroll
  for (int mi = 0; mi < 4; mi++)
    #pragma unroll
    for (int ni = 0; ni < 4; ni++)
      acc[mi][ni] = (f32x4)(0.f);

  for (int k0 = 0; k0 < K; k0 += 32){
    uint4 a0 = *(const uint4*)(A  + Aoff0 + k0);
    uint4 a1 = *(const uint4*)(A  + Aoff1 + k0);
    uint4 b0 = *(const uint4*)(Bw + Boff0 + k0);
    uint4 b1 = *(const uint4*)(Bw + Boff1 + k0);
    __syncthreads();
    *(uint4*)&As[wp0] = a0;
    *(uint4*)&As[wp1] = a1;
    *(uint4*)&Bs[wp0] = b0;
    *(uint4*)&Bs[wp1] = b1;
    __syncthreads();
    bf16x8 af[4], bfv[4];
    #pragma unroll
    for (int i = 0; i < 4; i++){
      af[i]  = *(const bf16x8*)&As[aoff[i]];
      bfv[i] = *(const bf16x8*)&Bs[boff[i]];
    }
    #pragma unroll
    for (int mi = 0; mi < 4; mi++)
      #pragma unroll
      for (int ni = 0; ni < 4; ni++)
        acc[mi][ni] = __builtin_amdgcn_mfma_f32_16x16x32_bf16(af[mi], bfv[ni], acc[mi][ni], 0, 0, 0);
  }

  #pragma unroll
  for (int mi = 0; mi < 4; mi++){
    #pragma unroll
    for (int ni = 0; ni < 4; ni++){
      #pragma unroll
      for (int i = 0; i < 4; i++){
        int m = m0 + wr*64 + mi*16 + (lane>>4)*4 + i;   // C/D: row=(lane>>4)*4+reg
        int n = n0 + wc*64 + ni*16 + (lane&15);          //      col=lane&15
        if (n >= Nreal) continue;
        float v = acc[mi][ni][i];
        if (MODE == 0){
          ((__hip_bfloat16*)Optr)[(size_t)m*Nreal + n] = __float2bfloat16(v);
        } else if (MODE == 1){
          ((__hip_bfloat16*)Optr)[(size_t)m*Nreal + n] = __float2bfloat16(v + bias[n]);
        } else if (MODE == 2){
          int nf = m >> 10, hw = m & (HW-1);
          int bb = nf >> 4, f = nf & (F_-1);
          size_t urow = ((size_t)((bb << 10) | hw))*F_ + f;
          ((__hip_bfloat16*)Optr)[urow*CEXP + n] = __float2bfloat16(v + bias[n]);
        } else {
          int st = c0tok + m;
          int sq = st >> 4, f = st & (F_-1);
          int bb = sq >> 10, hw = sq & (HW-1);
          size_t vrow = ((size_t)((bb << 4) | f))*HW + hw;
          ((__hip_bfloat16*)Optr)[vrow*CEXP + n] = __float2bfloat16(v);
        }
      }
    }
  }
}

// ---------------- fused conv1d + SSD + gate + RMSNorm (register-resident x path) --------
// One block per sequence (256 threads). Thread owns cols c0=tid*4 .. c0+3 of D_INNER.
// LDS ~45KB -> 3 blocks/CU.
__global__ __launch_bounds__(256,3) void ssm_kernel(
    const __hip_bfloat16* __restrict__ Zc,   // (SEQ, F_, D_IN_PROJ) bf16 chunk
    const float* __restrict__ conv_w,  // (CONV_DIM, 4)
    const float* __restrict__ conv_b,  // (CONV_DIM)
    const float* __restrict__ dt_bias, // (NHEADS)
    const float* __restrict__ A_log,   // (NHEADS)
    const float* __restrict__ Dp,      // (NHEADS)
    const float* __restrict__ rms_w,   // (D_INNER)
    __hip_bfloat16* __restrict__ Yc)   // (SEQ, F_, D_INNER) bf16
{
  __shared__ float bc[F_][257];                 // silu(conv) of B(0..127),C(128..255)
  __shared__ __hip_bfloat16 wts[F_][F_][NHEADS];
  __shared__ float dts[F_][NHEADS];
  __shared__ float cums[F_][NHEADS];
  __shared__ float scor[F_][F_+1];
  __shared__ float red[256][17];
  __shared__ float rinv[F_];
  const int tid = threadIdx.x;
  const __hip_bfloat16* Zb = Zc + (size_t)blockIdx.x * F_ * D_IN_PROJ;
  __hip_bfloat16* Yb = Yc + (size_t)blockIdx.x * F_ * D_INNER;

  // dt = softplus(raw + dt_bias)
  {
    int t = tid >> 4, h = tid & 15;
    float v = __bfloat162float(Zb[t*D_IN_PROJ + (D_INNER + CONV_DIM) + h]) + dt_bias[h];
    dts[t][h] = (v > 20.f) ? v : log1pf(expf(v));
  }
  // B/C conv + silu: conv channel cc = D_INNER + tid, raw col = D_INNER + cc
  {
    const int cc = D_INNER + tid;
    const float4 cw = *(const float4*)&conv_w[cc*4];
    const float cb = conv_b[cc];
    float r0 = 0.f, r1 = 0.f, r2 = 0.f, r3 = 0.f;
    #pragma unroll
    for (int t = 0; t < F_; t++){
      r0 = r1; r1 = r2; r2 = r3;
      r3 = __bfloat162float(Zb[t*D_IN_PROJ + D_INNER + cc]);
      float a = cb + r0*cw.x + r1*cw.y + r2*cw.z + r3*cw.w;
      bc[t][tid] = a / (1.f + expf(-a));
    }
  }
  __syncthreads();
  // cumulative dt*A per head
  if (tid < NHEADS){
    float A = -expf(A_log[tid]);
    float c = 0.f;
    for (int t = 0; t < F_; t++){ c += dts[t][tid]*A; cums[t][tid] = c; }
  }
  // scores[t][s] = C[t] . B[s]
  {
    int t = tid >> 4, s = tid & 15;
    float acc = 0.f;
    #pragma unroll 8
    for (int n = 0; n < D_STATE; n++)
      acc += bc[t][128 + n] * bc[s][n];
    scor[t][s] = acc;
  }
  __syncthreads();
  // wts[t][s][h] (bf16)
  #pragma unroll
  for (int rep = 0; rep < 16; rep++){
    int i = rep*256 + tid;
    int h = i & 15, s = (i >> 4) & 15, t = i >> 8;
    float v = 0.f;
    if (s <= t) v = scor[t][s] * expf(cums[t][h] - cums[s][h]) * dts[s][h];
    wts[t][s][h] = __float2bfloat16(v);
  }
  __syncthreads();

  // ---- register-resident x path ----
  const int c0 = tid*4;
  const int h  = tid >> 4;
  const float Dh = Dp[h];
  float4 cw0 = *(const float4*)&conv_w[(c0+0)*4];
  float4 cw1 = *(const float4*)&conv_w[(c0+1)*4];
  float4 cw2 = *(const float4*)&conv_w[(c0+2)*4];
  float4 cw3 = *(const float4*)&conv_w[(c0+3)*4];
  float4 cb4 = *(const float4*)&conv_b[c0];
  float y[F_][4];
  #pragma unroll
  for (int t = 0; t < F_; t++){ y[t][0]=0.f; y[t][1]=0.f; y[t][2]=0.f; y[t][3]=0.f; }
  float w0[4] = {0,0,0,0}, w1[4] = {0,0,0,0}, w2[4] = {0,0,0,0}, w3[4] = {0,0,0,0};
  #pragma unroll
  for (int s = 0; s < F_; s++){
    union { ushort4 u; __hip_bfloat16 hh[4]; } rv;
    rv.u = *(const ushort4*)&Zb[s*D_IN_PROJ + D_INNER + c0];
    #pragma unroll
    for (int j = 0; j < 4; j++){ w0[j]=w1[j]; w1[j]=w2[j]; w2[j]=w3[j]; }
    w3[0]=__bfloat162float(rv.hh[0]); w3[1]=__bfloat162float(rv.hh[1]);
    w3[2]=__bfloat162float(rv.hh[2]); w3[3]=__bfloat162float(rv.hh[3]);
    float xs[4];
    {
      float a;
      a = cb4.x + w0[0]*cw0.x + w1[0]*cw0.y + w2[0]*cw0.z + w3[0]*cw0.w; xs[0] = a/(1.f+expf(-a));
      a = cb4.y + w0[1]*cw1.x + w1[1]*cw1.y + w2[1]*cw1.z + w3[1]*cw1.w; xs[1] = a/(1.f+expf(-a));
      a = cb4.z + w0[2]*cw2.x + w1[2]*cw2.y + w2[2]*cw2.z + w3[2]*cw2.w; xs[2] = a/(1.f+expf(-a));
      a = cb4.w + w0[3]*cw3.x + w1[3]*cw3.y + w2[3]*cw3.z + w3[3]*cw3.w; xs[3] = a/(1.f+expf(-a));
    }
    #pragma unroll
    for (int j = 0; j < 4; j++) y[s][j] += Dh*xs[j];
    #pragma unroll
    for (int t = 0; t < F_; t++){
      if (t < s) continue;                       // compile-time eliminated
      float wv = __bfloat162float(wts[t][s][h]);
      y[t][0] += wv*xs[0]; y[t][1] += wv*xs[1];
      y[t][2] += wv*xs[2]; y[t][3] += wv*xs[3];
    }
  }
  // gate + per-t squared partials
  float part[F_];
  #pragma unroll
  for (int t = 0; t < F_; t++){
    union { ushort4 u; __hip_bfloat16 hh[4]; } zv;
    zv.u = *(const ushort4*)&Zb[t*D_IN_PROJ + c0];
    float p = 0.f;
    #pragma unroll
    for (int j = 0; j < 4; j++){
      float z = __bfloat162float(zv.hh[j]);
      float g = z / (1.f + expf(-z));
      y[t][j] *= g;
      p += y[t][j]*y[t][j];
    }
    part[t] = p;
    red[tid][t] = p;
  }
  __syncthreads();
  // reduce 256 -> 16 -> 1 per t (reuse scor)
  {
    int t = tid >> 4, seg = tid & 15;
    float s2 = 0.f;
    #pragma unroll
    for (int j = 0; j < 16; j++) s2 += red[seg*16 + j][t];
    scor[t][seg] = s2;
  }
  __syncthreads();
  if (tid < F_){
    float s = 0.f;
    #pragma unroll
    for (int j = 0; j < 16; j++) s += scor[tid][j];
    rinv[tid] = rsqrtf(s / D_INNER + 1e-5f);
  }
  __syncthreads();
  // normalize + rms_w + write bf16 (8B per thread per t)
  const float4 rw = *(const float4*)&rms_w[c0];
  #pragma unroll
  for (int t = 0; t < F_; t++){
    float ri = rinv[t];
    union { ushort4 u; __hip_bfloat16 hh[4]; } ov;
    ov.hh[0] = __float2bfloat16(y[t][0]*ri*rw.x);
    ov.hh[1] = __float2bfloat16(y[t][1]*ri*rw.y);
    ov.hh[2] = __float2bfloat16(y[t][2]*ri*rw.z);
    ov.hh[3] = __float2bfloat16(y[t][3]*ri*rw.w);
    *(ushort4*)&Yb[t*D_INNER + c0] = ov.u;
  }
  (void)part;
}

// ---------------- launcher ----------------
// workspace (float offsets), peak ~169 MiB:
//   Xg  f32  [0, 10485760)  -> V bf16 (reuse)
//   X0  bf16 [10485760, 15728640) -> C2 (reuse)
//   X1  bf16 [15728640, 20971520) -> P  (reuse)
//   U   bf16 [20971520, 29360128)
//   weights bf16 [29360128, 30547968)
//   Z   bf16 [30547968, 40050688)   8192 x 2320
//   Ycb bf16 [40050688, 44244992)   8192 x 1024
extern "C" void kernel_launch(void* const* d_in, const int* in_sizes, int n_in,
                              void* d_out, int out_size, void* d_ws, size_t ws_size,
                              hipStream_t stream)
{
  const float* x         = (const float*)d_in[0];
  const float* norm_w    = (const float*)d_in[1];
  const float* norm_b    = (const float*)d_in[2];
  const float* proj_in_w = (const float*)d_in[3];
  const float* proj_in_b = (const float*)d_in[4];
  const float* expand_w  = (const float*)d_in[5];
  const float* expand_b  = (const float*)d_in[6];
  const float* in_proj_w = (const float*)d_in[7];
  const float* conv_w    = (const float*)d_in[8];
  const float* conv_b    = (const float*)d_in[9];
  const float* dt_bias   = (const float*)d_in[10];
  const float* A_log     = (const float*)d_in[11];
  const float* Dvec      = (const float*)d_in[12];
  const float* rms_w     = (const float*)d_in[13];
  const float* out_proj_w= (const float*)d_in[14];
  const float* collapse_w= (const float*)d_in[15];
  const float* collapse_b= (const float*)d_in[16];
  const float* proj_out_w= (const float*)d_in[17];
  const float* proj_out_b= (const float*)d_in[18];
  const float* gamma     = (const float*)d_in[19];
  float* out = (float*)d_out;

  float* WS = (float*)d_ws;
  float*          Xg  = WS;
  __hip_bfloat16* V   = (__hip_bfloat16*)WS;                   // reuses Xg
  __hip_bfloat16* X0  = (__hip_bfloat16*)(WS + 10485760);
  __hip_bfloat16* C2  = (__hip_bfloat16*)(WS + 10485760);      // reuses X0
  __hip_bfloat16* X1  = (__hip_bfloat16*)(WS + 15728640);
  __hip_bfloat16* P   = (__hip_bfloat16*)(WS + 15728640);      // reuses X1
  __hip_bfloat16* U   = (__hip_bfloat16*)(WS + 20971520);
  __hip_bfloat16* Wb  = (__hip_bfloat16*)(WS + 29360128);
  __hip_bfloat16* Wob = (__hip_bfloat16*)(WS + 29982720);
  __hip_bfloat16* Wpb = (__hip_bfloat16*)(WS + 30244864);
  __hip_bfloat16* Web = (__hip_bfloat16*)(WS + 30306304);
  __hip_bfloat16* Wcb = (__hip_bfloat16*)(WS + 30388224);
  __hip_bfloat16* Wqb = (__hip_bfloat16*)(WS + 30486528);
  __hip_bfloat16* Z   = (__hip_bfloat16*)(WS + 30547968);
  __hip_bfloat16* Ycb = (__hip_bfloat16*)(WS + 40050688);

  // 0) weight conversions
  cvt_pad_kernel<<<(NPAD*CEXP+255)/256, 256, 0, stream>>>(in_proj_w, Wb, D_IN_PROJ, NPAD, CEXP);
  cvt_pad_kernel<<<(CEXP*D_INNER+255)/256, 256, 0, stream>>>(out_proj_w, Wob, CEXP, CEXP, D_INNER);
  cvt_pad_kernel<<<(C0PAD*C0+255)/256, 256, 0, stream>>>(proj_in_w, Wpb, C0, C0PAD, C0);
  cvt_pad_kernel<<<(CEXP*C0+255)/256, 256, 0, stream>>>(expand_w, Web, CEXP, CEXP, C0);
  cvt_pad_kernel<<<(C0PAD*CEXP+255)/256, 256, 0, stream>>>(collapse_w, Wcb, C0, C0PAD, CEXP);
  cvt_pad_kernel<<<(C0PAD*C0+255)/256, 256, 0, stream>>>(proj_out_w, Wqb, C0, C0PAD, C0);
  // 1) GroupNorm
  gn_kernel<<<dim3(GROUPS, NB), 256, 0, stream>>>(x, norm_w, norm_b, Xg);
  // 2) frames -> token-major bf16
  tok_cvt_kernel<<<dim3(HW/64, C0/64, NB), 256, 0, stream>>>(Xg, X0);
  // 3) proj_in
  mfma_nt_kernel<1><<<dim3(C0PAD/128, NTOK/128), 256, 0, stream>>>(
      X0, Wpb, X1, C0, C0, 0, proj_in_b);
  // 4) expand, rows permuted frame->seq
  mfma_nt_kernel<2><<<dim3(CEXP/128, NTOK/128), 256, 0, stream>>>(
      X1, Web, U, CEXP, C0, 0, expand_b);
  // 5) chunked mamba
  for (int c = 0; c < NCHUNK; c++){
    const __hip_bfloat16* Uc = U + (size_t)c*TOK_PER*CEXP;
    mfma_nt_kernel<0><<<dim3(NPAD/128, TOK_PER/128), 256, 0, stream>>>(
        Uc, Wb, Z, D_IN_PROJ, CEXP, 0, nullptr);
    ssm_kernel<<<SEQ_PER, 256, 0, stream>>>(
        Z, conv_w, conv_b, dt_bias, A_log, Dvec, rms_w, Ycb);
    mfma_nt_kernel<3><<<dim3(CEXP/128, TOK_PER/128), 256, 0, stream>>>(
        Ycb, Wob, V, CEXP, D_INNER, c*TOK_PER, nullptr);
  }
  // 6) collapse (+bias)
  mfma_nt_kernel<1><<<dim3(C0PAD/128, NTOK/128), 256, 0, stream>>>(
      V, Wcb, C2, C0, CEXP, 0, collapse_b);
  // 7) proj_out (+bias)
  mfma_nt_kernel<1><<<dim3(C0PAD/128, NTOK/128), 256, 0, stream>>>(
      C2, Wqb, P, C0, C0, 0, proj_out_b);
  // 8) final residual transpose
  final_kernel<<<dim3(HW/64, C0/64, NB), 256, 0, stream>>>(P, x, gamma, out);
}

// Round 8
// 660.867 us; speedup vs baseline: 6.4668x; 1.2502x over previous
//
#include <hip/hip_runtime.h>
#include <hip/hip_bf16.h>

// ---------------- problem constants ----------------
#define B_ 2
#define F_ 16
#define Hs 32
#define Ws 32
#define C0 320
#define CEXP 512
#define D_INNER 1024
#define NHEADS 16
#define HEADDIM 64
#define D_STATE 128
#define D_CONV 4
#define CONV_DIM (D_INNER + 2*D_STATE)              // 1280
#define D_IN_PROJ (2*D_INNER + 2*D_STATE + NHEADS)  // 2320
#define NPAD 2432                                   // 19*128 padded in_proj rows
#define C0PAD 384                                   // 3*128 padded 320-row weights
#define GROUPS 32
#define NB (B_*F_)        // 32 frames
#define HW (Hs*Ws)        // 1024 spatial
#define NSEQ (B_*HW)      // 2048 sequences
#define NTOK (NSEQ*F_)    // 32768 tokens
#define NCHUNK 4
#define SEQ_PER (NSEQ/NCHUNK)   // 512
#define TOK_PER (SEQ_PER*F_)    // 8192

typedef __bf16 bf16x8 __attribute__((ext_vector_type(8)));
typedef float f32x4 __attribute__((ext_vector_type(4)));

// ---------------- GroupNorm (f32 frames) ----------------
__global__ __launch_bounds__(256) void gn_kernel(const float* __restrict__ x,
    const float* __restrict__ w, const float* __restrict__ b, float* __restrict__ out)
{
  const int CG = C0/GROUPS;            // 10
  const int NEL = CG*HW;               // 10240
  int g = blockIdx.x, n = blockIdx.y;
  const float* xp = x + ((size_t)n*C0 + (size_t)g*CG)*HW;
  float* op = out + ((size_t)n*C0 + (size_t)g*CG)*HW;
  float s = 0.f, ss = 0.f;
  for (int i = threadIdx.x; i < NEL; i += 256){ float v = xp[i]; s += v; ss += v*v; }
  __shared__ float rs[256], rq[256];
  rs[threadIdx.x] = s; rq[threadIdx.x] = ss;
  __syncthreads();
  for (int o = 128; o > 0; o >>= 1){
    if (threadIdx.x < o){ rs[threadIdx.x] += rs[threadIdx.x+o]; rq[threadIdx.x] += rq[threadIdx.x+o]; }
    __syncthreads();
  }
  float mu  = rs[0] / NEL;
  float var = rq[0] / NEL - mu*mu;
  float inv = rsqrtf(var + 1e-5f);
  for (int i = threadIdx.x; i < NEL; i += 256){
    int c = g*CG + i/HW;
    op[i] = (xp[i] - mu)*inv*w[c] + b[c];
  }
}

// ---------------- weight f32 -> bf16 conversion (optional row padding) ----------------
__global__ __launch_bounds__(256) void cvt_pad_kernel(const float* __restrict__ w,
    __hip_bfloat16* __restrict__ o, int Nreal, int Npad, int K)
{
  int i = blockIdx.x*256 + threadIdx.x;
  if (i >= Npad*K) return;
  int n = i / K;
  int k = i - n*K;
  float v = (n < Nreal) ? w[(size_t)n*K + k] : 0.f;
  o[i] = __float2bfloat16(v);
}

// ---------------- frames f32 (n,c,hw) -> token-major bf16 (n*HW+hw, c) ----------------
__global__ __launch_bounds__(256) void tok_cvt_kernel(const float* __restrict__ Xg,
    __hip_bfloat16* __restrict__ X0)
{
  __shared__ float t[64][65];
  const int n = blockIdx.z, c0 = blockIdx.y*64, hw0 = blockIdx.x*64;
  const int r = threadIdx.x >> 2, sl = threadIdx.x & 3;
  size_t ibase = ((size_t)n*C0 + c0 + r)*HW + hw0 + sl*16;
  #pragma unroll
  for (int j = 0; j < 16; j++) t[r][sl*16 + j] = Xg[ibase + j];   // t[c_local][hw_local]
  __syncthreads();
  __hip_bfloat16* Orow = X0 + ((size_t)(n*HW + hw0 + r))*C0 + c0 + sl*16;
  union { uint4 u; __hip_bfloat16 h[8]; } v;
  #pragma unroll
  for (int half = 0; half < 2; half++){
    #pragma unroll
    for (int j = 0; j < 8; j++) v.h[j] = __float2bfloat16(t[sl*16 + half*8 + j][r]);
    *(uint4*)(Orow + half*8) = v.u;
  }
}

// ---------------- final: P bf16 tokens -> out f32 frames with residual ----------------
__global__ __launch_bounds__(256) void final_kernel(const __hip_bfloat16* __restrict__ P,
    const float* __restrict__ x, const float* __restrict__ gammap, float* __restrict__ out)
{
  __shared__ float t[64][65];
  const int n = blockIdx.z, c0 = blockIdx.y*64, hw0 = blockIdx.x*64;
  const int r = threadIdx.x >> 2, sl = threadIdx.x & 3;
  const __hip_bfloat16* Pr = P + ((size_t)(n*HW + hw0 + r))*C0 + c0 + sl*16;
  union { uint4 u; __hip_bfloat16 h[8]; } v;
  #pragma unroll
  for (int half = 0; half < 2; half++){
    v.u = *(const uint4*)(Pr + half*8);
    #pragma unroll
    for (int j = 0; j < 8; j++) t[sl*16 + half*8 + j][r] = __bfloat162float(v.h[j]);
  }
  __syncthreads();
  const float g = *gammap;
  size_t obase = ((size_t)n*C0 + c0 + r)*HW + hw0 + sl*16;
  #pragma unroll
  for (int j = 0; j < 16; j++)
    out[obase + j] = x[obase + j] + g*t[r][sl*16 + j];
}

// ---------------- bf16 MFMA GEMM NT: O = A(MxK) * Bw(NpadxK)^T (+bias[n]) ----------------
// 128x128 tile, BK=32, 4 waves (2x2), each wave 64x64 via 4x4 16x16x32 mfma frags.
// LDS [128 rows][32 k] bf16, 16B-granule XOR swizzle: slot ^= (row>>1)&3.
// MODE 0: bf16 out (no bias), O[m*Nreal+n], guard n<Nreal   (in_proj -> Z)
// MODE 1: bf16 out +bias, O[m*Nreal+n], guard n<Nreal       (proj_in, collapse, proj_out)
// MODE 2: bf16 out +bias, frame-tok -> seq-tok row permute  (expand -> U)
// MODE 3: bf16 out, seq-tok -> frame-tok row permute        (out_proj -> V)
template<int MODE>
__global__ __launch_bounds__(256) void mfma_nt_kernel(
    const __hip_bfloat16* __restrict__ A,   // M x K
    const __hip_bfloat16* __restrict__ Bw,  // Npad x K
    void* __restrict__ Optr,
    int Nreal, int K, int c0tok,
    const float* __restrict__ bias)
{
  __shared__ unsigned short As[128*32];
  __shared__ unsigned short Bs[128*32];
  const int tid = threadIdx.x;
  const int lane = tid & 63;
  const int m0 = blockIdx.y * 128;
  const int n0 = blockIdx.x * 128;

  const int row0 = tid >> 2;
  const int sl   = tid & 3;
  const int row1 = row0 + 64;
  const int sw0  = sl ^ ((row0 >> 1) & 3);
  const int sw1  = sl ^ ((row1 >> 1) & 3);
  const size_t Aoff0 = (size_t)(m0 + row0)*K + sl*8;
  const size_t Aoff1 = (size_t)(m0 + row1)*K + sl*8;
  const size_t Boff0 = (size_t)(n0 + row0)*K + sl*8;
  const size_t Boff1 = (size_t)(n0 + row1)*K + sl*8;
  const int wp0 = row0*32 + sw0*8;
  const int wp1 = row1*32 + sw1*8;

  const int wid = tid >> 6, wr = wid >> 1, wc = wid & 1;
  const int fr = lane & 15, ks = lane >> 4;
  int aoff[4], boff[4];
  #pragma unroll
  for (int i = 0; i < 4; i++){
    int ra = wr*64 + i*16 + fr;
    aoff[i] = ra*32 + ((ks ^ ((ra>>1)&3))<<3);
    int rb = wc*64 + i*16 + fr;
    boff[i] = rb*32 + ((ks ^ ((rb>>1)&3))<<3);
  }

  f32x4 acc[4][4];
  #pragma unroll
  for (int mi = 0; mi < 4; mi++)
    #pragma unroll
    for (int ni = 0; ni < 4; ni++)
      acc[mi][ni] = (f32x4)(0.f);

  for (int k0 = 0; k0 < K; k0 += 32){
    uint4 a0 = *(const uint4*)(A  + Aoff0 + k0);
    uint4 a1 = *(const uint4*)(A  + Aoff1 + k0);
    uint4 b0 = *(const uint4*)(Bw + Boff0 + k0);
    uint4 b1 = *(const uint4*)(Bw + Boff1 + k0);
    __syncthreads();
    *(uint4*)&As[wp0] = a0;
    *(uint4*)&As[wp1] = a1;
    *(uint4*)&Bs[wp0] = b0;
    *(uint4*)&Bs[wp1] = b1;
    __syncthreads();
    bf16x8 af[4], bfv[4];
    #pragma unroll
    for (int i = 0; i < 4; i++){
      af[i]  = *(const bf16x8*)&As[aoff[i]];
      bfv[i] = *(const bf16x8*)&Bs[boff[i]];
    }
    #pragma unroll
    for (int mi = 0; mi < 4; mi++)
      #pragma unroll
      for (int ni = 0; ni < 4; ni++)
        acc[mi][ni] = __builtin_amdgcn_mfma_f32_16x16x32_bf16(af[mi], bfv[ni], acc[mi][ni], 0, 0, 0);
  }

  #pragma unroll
  for (int mi = 0; mi < 4; mi++){
    #pragma unroll
    for (int ni = 0; ni < 4; ni++){
      #pragma unroll
      for (int i = 0; i < 4; i++){
        int m = m0 + wr*64 + mi*16 + (lane>>4)*4 + i;   // C/D: row=(lane>>4)*4+reg
        int n = n0 + wc*64 + ni*16 + (lane&15);          //      col=lane&15
        if (n >= Nreal) continue;
        float v = acc[mi][ni][i];
        if (MODE == 0){
          ((__hip_bfloat16*)Optr)[(size_t)m*Nreal + n] = __float2bfloat16(v);
        } else if (MODE == 1){
          ((__hip_bfloat16*)Optr)[(size_t)m*Nreal + n] = __float2bfloat16(v + bias[n]);
        } else if (MODE == 2){
          int nf = m >> 10, hw = m & (HW-1);
          int bb = nf >> 4, f = nf & (F_-1);
          size_t urow = ((size_t)((bb << 10) | hw))*F_ + f;
          ((__hip_bfloat16*)Optr)[urow*CEXP + n] = __float2bfloat16(v + bias[n]);
        } else {
          int st = c0tok + m;
          int sq = st >> 4, f = st & (F_-1);
          int bb = sq >> 10, hw = sq & (HW-1);
          size_t vrow = ((size_t)((bb << 4) | f))*HW + hw;
          ((__hip_bfloat16*)Optr)[vrow*CEXP + n] = __float2bfloat16(v);
        }
      }
    }
  }
}

// ---------------- fused conv1d + SSD + gate + RMSNorm (register x, packed y) ----------
// One block per sequence (256 threads). Thread owns cols c0=tid*4 .. c0+3 of D_INNER.
// xs[16][4] f32 stays in regs; gated y stored packed bf16 (y_pk[16][2] u32).
// LDS ~44KB -> 3 blocks/CU; VGPR ~130 (launch_bounds(256,1): no forced spill).
__global__ __launch_bounds__(256,1) void ssm_kernel(
    const __hip_bfloat16* __restrict__ Zc,   // (SEQ, F_, D_IN_PROJ) bf16 chunk
    const float* __restrict__ conv_w,  // (CONV_DIM, 4)
    const float* __restrict__ conv_b,  // (CONV_DIM)
    const float* __restrict__ dt_bias, // (NHEADS)
    const float* __restrict__ A_log,   // (NHEADS)
    const float* __restrict__ Dp,      // (NHEADS)
    const float* __restrict__ rms_w,   // (D_INNER)
    __hip_bfloat16* __restrict__ Yc)   // (SEQ, F_, D_INNER) bf16
{
  __shared__ float bc[F_][257];                 // silu(conv) of B(0..127),C(128..255)
  __shared__ __hip_bfloat16 wts[F_][F_][NHEADS];
  __shared__ float dts[F_][NHEADS];
  __shared__ float cums[F_][NHEADS];
  __shared__ float scor[F_][F_+1];
  __shared__ float red[256][17];
  __shared__ float rinv[F_];
  const int tid = threadIdx.x;
  const __hip_bfloat16* Zb = Zc + (size_t)blockIdx.x * F_ * D_IN_PROJ;
  __hip_bfloat16* Yb = Yc + (size_t)blockIdx.x * F_ * D_INNER;

  // dt = softplus(raw + dt_bias)
  {
    int t = tid >> 4, h = tid & 15;
    float v = __bfloat162float(Zb[t*D_IN_PROJ + (D_INNER + CONV_DIM) + h]) + dt_bias[h];
    dts[t][h] = (v > 20.f) ? v : log1pf(expf(v));
  }
  // B/C conv + silu
  {
    const int cc = D_INNER + tid;
    const float4 cw = *(const float4*)&conv_w[cc*4];
    const float cb = conv_b[cc];
    float r0 = 0.f, r1 = 0.f, r2 = 0.f, r3 = 0.f;
    #pragma unroll
    for (int t = 0; t < F_; t++){
      r0 = r1; r1 = r2; r2 = r3;
      r3 = __bfloat162float(Zb[t*D_IN_PROJ + D_INNER + cc]);
      float a = cb + r0*cw.x + r1*cw.y + r2*cw.z + r3*cw.w;
      bc[t][tid] = a / (1.f + expf(-a));
    }
  }
  __syncthreads();
  // cumulative dt*A per head
  if (tid < NHEADS){
    float A = -expf(A_log[tid]);
    float c = 0.f;
    for (int t = 0; t < F_; t++){ c += dts[t][tid]*A; cums[t][tid] = c; }
  }
  // scores[t][s] = C[t] . B[s]
  {
    int t = tid >> 4, s = tid & 15;
    float acc = 0.f;
    #pragma unroll 8
    for (int n = 0; n < D_STATE; n++)
      acc += bc[t][128 + n] * bc[s][n];
    scor[t][s] = acc;
  }
  __syncthreads();
  // wts[t][s][h] (bf16)
  #pragma unroll
  for (int rep = 0; rep < 16; rep++){
    int i = rep*256 + tid;
    int h = i & 15, s = (i >> 4) & 15, t = i >> 8;
    float v = 0.f;
    if (s <= t) v = scor[t][s] * expf(cums[t][h] - cums[s][h]) * dts[s][h];
    wts[t][s][h] = __float2bfloat16(v);
  }
  __syncthreads();

  // ---- register-resident x path ----
  const int c0 = tid*4;
  const int h  = tid >> 4;
  const float Dh = Dp[h];
  const float4 cw0 = *(const float4*)&conv_w[(c0+0)*4];
  const float4 cw1 = *(const float4*)&conv_w[(c0+1)*4];
  const float4 cw2 = *(const float4*)&conv_w[(c0+2)*4];
  const float4 cw3 = *(const float4*)&conv_w[(c0+3)*4];
  const float4 cb4 = *(const float4*)&conv_b[c0];

  // conv1d + silu -> xs[16][4] (static indices, stays in VGPRs)
  float xs[F_][4];
  {
    float w0[4] = {0,0,0,0}, w1[4] = {0,0,0,0}, w2[4] = {0,0,0,0}, w3[4] = {0,0,0,0};
    #pragma unroll
    for (int s = 0; s < F_; s++){
      union { ushort4 u; __hip_bfloat16 hh[4]; } rv;
      rv.u = *(const ushort4*)&Zb[s*D_IN_PROJ + D_INNER + c0];
      #pragma unroll
      for (int j = 0; j < 4; j++){ w0[j]=w1[j]; w1[j]=w2[j]; w2[j]=w3[j]; }
      w3[0]=__bfloat162float(rv.hh[0]); w3[1]=__bfloat162float(rv.hh[1]);
      w3[2]=__bfloat162float(rv.hh[2]); w3[3]=__bfloat162float(rv.hh[3]);
      float a;
      a = cb4.x + w0[0]*cw0.x + w1[0]*cw0.y + w2[0]*cw0.z + w3[0]*cw0.w; xs[s][0] = a/(1.f+expf(-a));
      a = cb4.y + w0[1]*cw1.x + w1[1]*cw1.y + w2[1]*cw1.z + w3[1]*cw1.w; xs[s][1] = a/(1.f+expf(-a));
      a = cb4.z + w0[2]*cw2.x + w1[2]*cw2.y + w2[2]*cw2.z + w3[2]*cw2.w; xs[s][2] = a/(1.f+expf(-a));
      a = cb4.w + w0[3]*cw3.x + w1[3]*cw3.y + w2[3]*cw3.z + w3[3]*cw3.w; xs[s][3] = a/(1.f+expf(-a));
    }
  }

  // per-t: SSD sum (f32), gate, square-partial, pack to bf16 pair regs
  unsigned int y_pk[F_][2];
  #pragma unroll
  for (int t = 0; t < F_; t++){
    float y0 = Dh*xs[t][0], y1 = Dh*xs[t][1], y2 = Dh*xs[t][2], y3 = Dh*xs[t][3];
    #pragma unroll
    for (int s = 0; s < F_; s++){
      if (s > t) continue;                      // compile-time eliminated
      float wv = __bfloat162float(wts[t][s][h]);
      y0 += wv*xs[s][0]; y1 += wv*xs[s][1];
      y2 += wv*xs[s][2]; y3 += wv*xs[s][3];
    }
    union { ushort4 u; __hip_bfloat16 hh[4]; } zv;
    zv.u = *(const ushort4*)&Zb[t*D_IN_PROJ + c0];
    float z0 = __bfloat162float(zv.hh[0]), z1 = __bfloat162float(zv.hh[1]);
    float z2 = __bfloat162float(zv.hh[2]), z3 = __bfloat162float(zv.hh[3]);
    y0 *= z0/(1.f+expf(-z0)); y1 *= z1/(1.f+expf(-z1));
    y2 *= z2/(1.f+expf(-z2)); y3 *= z3/(1.f+expf(-z3));
    red[tid][t] = y0*y0 + y1*y1 + y2*y2 + y3*y3;
    union { unsigned int u; unsigned short s2[2]; } p0, p1;
    // round-to-nearest bf16 pack
    __hip_bfloat16 b0 = __float2bfloat16(y0), b1 = __float2bfloat16(y1);
    __hip_bfloat16 b2 = __float2bfloat16(y2), b3 = __float2bfloat16(y3);
    p0.s2[0] = *(unsigned short*)&b0; p0.s2[1] = *(unsigned short*)&b1;
    p1.s2[0] = *(unsigned short*)&b2; p1.s2[1] = *(unsigned short*)&b3;
    y_pk[t][0] = p0.u; y_pk[t][1] = p1.u;
  }
  __syncthreads();
  // reduce 256 -> 16 -> 1 per t
  {
    int t = tid >> 4, seg = tid & 15;
    float s2 = 0.f;
    #pragma unroll
    for (int j = 0; j < 16; j++) s2 += red[seg*16 + j][t];
    scor[t][seg] = s2;
  }
  __syncthreads();
  if (tid < F_){
    float s = 0.f;
    #pragma unroll
    for (int j = 0; j < 16; j++) s += scor[tid][j];
    rinv[tid] = rsqrtf(s / D_INNER + 1e-5f);
  }
  __syncthreads();
  // unpack, normalize, write bf16
  const float4 rw = *(const float4*)&rms_w[c0];
  #pragma unroll
  for (int t = 0; t < F_; t++){
    float ri = rinv[t];
    union { unsigned int u; unsigned short s2[2]; } p0, p1;
    p0.u = y_pk[t][0]; p1.u = y_pk[t][1];
    union { unsigned int u; float f; } f0, f1, f2, f3;
    f0.u = (unsigned int)p0.s2[0] << 16; f1.u = (unsigned int)p0.s2[1] << 16;
    f2.u = (unsigned int)p1.s2[0] << 16; f3.u = (unsigned int)p1.s2[1] << 16;
    union { ushort4 u; __hip_bfloat16 hh[4]; } ov;
    ov.hh[0] = __float2bfloat16(f0.f*ri*rw.x);
    ov.hh[1] = __float2bfloat16(f1.f*ri*rw.y);
    ov.hh[2] = __float2bfloat16(f2.f*ri*rw.z);
    ov.hh[3] = __float2bfloat16(f3.f*ri*rw.w);
    *(ushort4*)&Yb[t*D_INNER + c0] = ov.u;
  }
}

// ---------------- launcher ----------------
// workspace (float offsets), peak ~169 MiB:
//   Xg  f32  [0, 10485760)  -> V bf16 (reuse)
//   X0  bf16 [10485760, 15728640) -> C2 (reuse)
//   X1  bf16 [15728640, 20971520) -> P  (reuse)
//   U   bf16 [20971520, 29360128)
//   weights bf16 [29360128, 30547968)
//   Z   bf16 [30547968, 40050688)   8192 x 2320
//   Ycb bf16 [40050688, 44244992)   8192 x 1024
extern "C" void kernel_launch(void* const* d_in, const int* in_sizes, int n_in,
                              void* d_out, int out_size, void* d_ws, size_t ws_size,
                              hipStream_t stream)
{
  const float* x         = (const float*)d_in[0];
  const float* norm_w    = (const float*)d_in[1];
  const float* norm_b    = (const float*)d_in[2];
  const float* proj_in_w = (const float*)d_in[3];
  const float* proj_in_b = (const float*)d_in[4];
  const float* expand_w  = (const float*)d_in[5];
  const float* expand_b  = (const float*)d_in[6];
  const float* in_proj_w = (const float*)d_in[7];
  const float* conv_w    = (const float*)d_in[8];
  const float* conv_b    = (const float*)d_in[9];
  const float* dt_bias   = (const float*)d_in[10];
  const float* A_log     = (const float*)d_in[11];
  const float* Dvec      = (const float*)d_in[12];
  const float* rms_w     = (const float*)d_in[13];
  const float* out_proj_w= (const float*)d_in[14];
  const float* collapse_w= (const float*)d_in[15];
  const float* collapse_b= (const float*)d_in[16];
  const float* proj_out_w= (const float*)d_in[17];
  const float* proj_out_b= (const float*)d_in[18];
  const float* gamma     = (const float*)d_in[19];
  float* out = (float*)d_out;

  float* WS = (float*)d_ws;
  float*          Xg  = WS;
  __hip_bfloat16* V   = (__hip_bfloat16*)WS;                   // reuses Xg
  __hip_bfloat16* X0  = (__hip_bfloat16*)(WS + 10485760);
  __hip_bfloat16* C2  = (__hip_bfloat16*)(WS + 10485760);      // reuses X0
  __hip_bfloat16* X1  = (__hip_bfloat16*)(WS + 15728640);
  __hip_bfloat16* P   = (__hip_bfloat16*)(WS + 15728640);      // reuses X1
  __hip_bfloat16* U   = (__hip_bfloat16*)(WS + 20971520);
  __hip_bfloat16* Wb  = (__hip_bfloat16*)(WS + 29360128);
  __hip_bfloat16* Wob = (__hip_bfloat16*)(WS + 29982720);
  __hip_bfloat16* Wpb = (__hip_bfloat16*)(WS + 30244864);
  __hip_bfloat16* Web = (__hip_bfloat16*)(WS + 30306304);
  __hip_bfloat16* Wcb = (__hip_bfloat16*)(WS + 30388224);
  __hip_bfloat16* Wqb = (__hip_bfloat16*)(WS + 30486528);
  __hip_bfloat16* Z   = (__hip_bfloat16*)(WS + 30547968);
  __hip_bfloat16* Ycb = (__hip_bfloat16*)(WS + 40050688);

  // 0) weight conversions
  cvt_pad_kernel<<<(NPAD*CEXP+255)/256, 256, 0, stream>>>(in_proj_w, Wb, D_IN_PROJ, NPAD, CEXP);
  cvt_pad_kernel<<<(CEXP*D_INNER+255)/256, 256, 0, stream>>>(out_proj_w, Wob, CEXP, CEXP, D_INNER);
  cvt_pad_kernel<<<(C0PAD*C0+255)/256, 256, 0, stream>>>(proj_in_w, Wpb, C0, C0PAD, C0);
  cvt_pad_kernel<<<(CEXP*C0+255)/256, 256, 0, stream>>>(expand_w, Web, CEXP, CEXP, C0);
  cvt_pad_kernel<<<(C0PAD*CEXP+255)/256, 256, 0, stream>>>(collapse_w, Wcb, C0, C0PAD, CEXP);
  cvt_pad_kernel<<<(C0PAD*C0+255)/256, 256, 0, stream>>>(proj_out_w, Wqb, C0, C0PAD, C0);
  // 1) GroupNorm
  gn_kernel<<<dim3(GROUPS, NB), 256, 0, stream>>>(x, norm_w, norm_b, Xg);
  // 2) frames -> token-major bf16
  tok_cvt_kernel<<<dim3(HW/64, C0/64, NB), 256, 0, stream>>>(Xg, X0);
  // 3) proj_in
  mfma_nt_kernel<1><<<dim3(C0PAD/128, NTOK/128), 256, 0, stream>>>(
      X0, Wpb, X1, C0, C0, 0, proj_in_b);
  // 4) expand, rows permuted frame->seq
  mfma_nt_kernel<2><<<dim3(CEXP/128, NTOK/128), 256, 0, stream>>>(
      X1, Web, U, CEXP, C0, 0, expand_b);
  // 5) chunked mamba
  for (int c = 0; c < NCHUNK; c++){
    const __hip_bfloat16* Uc = U + (size_t)c*TOK_PER*CEXP;
    mfma_nt_kernel<0><<<dim3(NPAD/128, TOK_PER/128), 256, 0, stream>>>(
        Uc, Wb, Z, D_IN_PROJ, CEXP, 0, nullptr);
    ssm_kernel<<<SEQ_PER, 256, 0, stream>>>(
        Z, conv_w, conv_b, dt_bias, A_log, Dvec, rms_w, Ycb);
    mfma_nt_kernel<3><<<dim3(CEXP/128, TOK_PER/128), 256, 0, stream>>>(
        Ycb, Wob, V, CEXP, D_INNER, c*TOK_PER, nullptr);
  }
  // 6) collapse (+bias)
  mfma_nt_kernel<1><<<dim3(C0PAD/128, NTOK/128), 256, 0, stream>>>(
      V, Wcb, C2, C0, CEXP, 0, collapse_b);
  // 7) proj_out (+bias)
  mfma_nt_kernel<1><<<dim3(C0PAD/128, NTOK/128), 256, 0, stream>>>(
      C2, Wqb, P, C0, C0, 0, proj_out_b);
  // 8) final residual transpose
  final_kernel<<<dim3(HW/64, C0/64, NB), 256, 0, stream>>>(P, x, gamma, out);
}